// Round 3
// baseline (394.187 us; speedup 1.0000x reference)
//
#include <hip/hip_runtime.h>

#define BATCH 2
#define SEQ 2048
#define EMBED 2048
#define NHEADS 32
#define NKV 8
#define HDIM 64
#define QKV_LD 3072  // fused [Q(2048) | K(512) | V(512)] row stride
#define LOG2E 1.44269504088896f

typedef __attribute__((ext_vector_type(8))) short short8;
typedef __attribute__((ext_vector_type(4))) float f32x4;

__device__ inline float hw_exp2(float x) { return __builtin_amdgcn_exp2f(x); }

__device__ inline ushort f2bf(float f) {
  union { float f; unsigned u; } v{f};
  unsigned r = v.u + 0x7FFF + ((v.u >> 16) & 1);
  return (ushort)(r >> 16);
}
__device__ inline float bf2f(ushort u) {
  union { unsigned u; float f; } v{((unsigned)u) << 16};
  return v.f;
}
__device__ inline unsigned fbits(float f) {
  union { float f; unsigned u; } v{f};
  return v.u;
}

__device__ inline void gload16(const ushort* g, ushort* l) {
  __builtin_amdgcn_global_load_lds(
      (const __attribute__((address_space(1))) unsigned*)g,
      (__attribute__((address_space(3))) unsigned*)l, 16, 0, 0);
}

// ---------------- fused fp32 -> bf16 convert (all 5 tensors, 1 launch) ----------------
// element ranges: x[0,8388608) wq[..12582912) wk[..13631488) wv[..14680064) wo[..18874368)
__global__ __launch_bounds__(256) void cvt_all(const float* __restrict__ x,
                                               const float* __restrict__ wq,
                                               const float* __restrict__ wk,
                                               const float* __restrict__ wv,
                                               const float* __restrict__ wo,
                                               ushort* __restrict__ xb,
                                               ushort* __restrict__ wqkv,
                                               ushort* __restrict__ wob) {
  size_t e = (size_t)(blockIdx.x * blockDim.x + threadIdx.x) * 8;
  const float* src;
  ushort* dst;
  if (e < 8388608u) { src = x + e; dst = xb + e; }
  else if (e < 12582912u) { size_t o = e - 8388608u; src = wq + o; dst = wqkv + o; }
  else if (e < 13631488u) { size_t o = e - 12582912u; src = wk + o; dst = wqkv + 4194304u + o; }
  else if (e < 14680064u) { size_t o = e - 13631488u; src = wv + o; dst = wqkv + 5242880u + o; }
  else { size_t o = e - 14680064u; src = wo + o; dst = wob + o; }
  float4 v0 = ((const float4*)src)[0];
  float4 v1 = ((const float4*)src)[1];
  union { uint4 v; ushort u[8]; } pk;
  pk.u[0] = f2bf(v0.x); pk.u[1] = f2bf(v0.y); pk.u[2] = f2bf(v0.z); pk.u[3] = f2bf(v0.w);
  pk.u[4] = f2bf(v1.x); pk.u[5] = f2bf(v1.y); pk.u[6] = f2bf(v1.z); pk.u[7] = f2bf(v1.w);
  *(uint4*)dst = pk.v;
}

// ---------------- bf16 MFMA GEMM (m97 structure): C[M,N] = A * B^T ----------------
template <typename OutT>
__global__ __launch_bounds__(256) void gemm_bf16(const ushort* __restrict__ A,
                                                 const ushort* __restrict__ B,
                                                 OutT* __restrict__ C,
                                                 int M, int N, int K) {
  __shared__ ushort As[128][32];
  __shared__ ushort Bs[128][32];
  const int tid = threadIdx.x;
  const int lane = tid & 63, wave = tid >> 6;
  const int quad = lane >> 4, l16 = lane & 15;
  const int m0 = blockIdx.y * 128, n0 = blockIdx.x * 128;
  const int wm = (wave >> 1) * 64, wn = (wave & 1) * 64;
  const int srow = lane >> 2, skq = (lane & 3) * 8;

  f32x4 acc[4][4] = {};
  for (int k0 = 0; k0 < K; k0 += 32) {
    const ushort* ga = A + (size_t)(m0 + wave * 32 + srow) * K + k0 + skq;
    const ushort* gb = B + (size_t)(n0 + wave * 32 + srow) * K + k0 + skq;
    __syncthreads();
    gload16(ga, &As[wave * 32][0]);
    gload16(ga + (size_t)16 * K, &As[wave * 32 + 16][0]);
    gload16(gb, &Bs[wave * 32][0]);
    gload16(gb + (size_t)16 * K, &Bs[wave * 32 + 16][0]);
    __syncthreads();
    short8 af[4], bf[4];
#pragma unroll
    for (int i = 0; i < 4; i++) af[i] = *(short8*)&As[wm + i * 16 + l16][quad * 8];
#pragma unroll
    for (int j = 0; j < 4; j++) bf[j] = *(short8*)&Bs[wn + j * 16 + l16][quad * 8];
#pragma unroll
    for (int i = 0; i < 4; i++)
#pragma unroll
      for (int j = 0; j < 4; j++)
        acc[i][j] = __builtin_amdgcn_mfma_f32_16x16x32_bf16(af[i], bf[j], acc[i][j], 0, 0, 0);
  }
#pragma unroll
  for (int i = 0; i < 4; i++) {
#pragma unroll
    for (int r = 0; r < 4; r++) {
      size_t rg = (size_t)(m0 + wm + i * 16 + quad * 4 + r);
#pragma unroll
      for (int j = 0; j < 4; j++) {
        float v = acc[i][j][r];
        int cg = n0 + wn + j * 16 + l16;
        if constexpr (sizeof(OutT) == 2)
          C[rg * N + cg] = f2bf(v);
        else
          C[rg * N + cg] = v;
      }
    }
  }
}

// ---------------- vectorized RoPE on fused QKV ----------------
// Q heads prescaled by 0.125*log2(e) (exp2-domain softmax downstream).
// thread = (tok, hh<40, g<4): handles dims [g*8, g*8+8) and [g*8+32, g*8+40).
__global__ __launch_bounds__(256) void rope_qk(ushort* __restrict__ t,
                                               const float* __restrict__ fc,
                                               const float* __restrict__ fs,
                                               int total) {
  int idx = blockIdx.x * blockDim.x + threadIdx.x;
  if (idx >= total) return;
  int g = idx & 3;
  int hh = (idx >> 2) % 40;
  int tok = idx / 160;
  int s = tok & (SEQ - 1);
  float scale = (hh < 32) ? 0.125f * LOG2E : 1.0f;
  ushort* p = t + (size_t)tok * QKV_LD + hh * 64 + g * 8;
  union { uint4 v; ushort u[8]; } lo, hi, olo, ohi;
  lo.v = *(const uint4*)p;
  hi.v = *(const uint4*)(p + 32);
  const float* fcb = fc + s * HDIM + g * 8;
  const float* fsb = fs + s * HDIM + g * 8;
  float4 c0a = ((const float4*)fcb)[0], c0b = ((const float4*)fcb)[1];
  float4 s0a = ((const float4*)fsb)[0], s0b = ((const float4*)fsb)[1];
  float4 c1a = ((const float4*)(fcb + 32))[0], c1b = ((const float4*)(fcb + 32))[1];
  float4 s1a = ((const float4*)(fsb + 32))[0], s1b = ((const float4*)(fsb + 32))[1];
  float cc0[8] = {c0a.x, c0a.y, c0a.z, c0a.w, c0b.x, c0b.y, c0b.z, c0b.w};
  float ss0[8] = {s0a.x, s0a.y, s0a.z, s0a.w, s0b.x, s0b.y, s0b.z, s0b.w};
  float cc1[8] = {c1a.x, c1a.y, c1a.z, c1a.w, c1b.x, c1b.y, c1b.z, c1b.w};
  float ss1[8] = {s1a.x, s1a.y, s1a.z, s1a.w, s1b.x, s1b.y, s1b.z, s1b.w};
#pragma unroll
  for (int j = 0; j < 8; j++) {
    float x0 = bf2f(lo.u[j]), x1 = bf2f(hi.u[j]);
    olo.u[j] = f2bf((x0 * cc0[j] - x1 * ss0[j]) * scale);
    ohi.u[j] = f2bf((x1 * cc1[j] + x0 * ss1[j]) * scale);
  }
  *(uint4*)p = olo.v;
  *(uint4*)(p + 32) = ohi.v;
}

// ---------------- MFMA flash attention v4 ----------------
// v1 staging/compute structure, UN-PAIRED for occupancy:
//  - one 64-row q-tile per block -> grid 32x64 = 2048 blocks (vs 1024);
//    LDS 27.6 KB -> 5 resident blocks/CU (20 waves) instead of grid-capped 4.
//  - heaviest q-tiles launch first (qt = 31 - blockIdx.x) for tail balance.
//  - T13 defer-max (THR=8, exp2 domain): skip o-rescale when max doesn't grow.
//  - T5 s_setprio(1) around MFMA clusters.
__global__ __launch_bounds__(256) void attn_mfma(const ushort* __restrict__ QKV,
                                                 ushort* __restrict__ O) {
  __shared__ ushort Ks[64][72];     // [key][d]
  __shared__ ushort Vt[64][72];     // [d][key]
  __shared__ ushort Pw[4][16][72];  // per-wave P[q][key]
  const int tid = threadIdx.x;
  const int lane = tid & 63, wave = tid >> 6;
  const int quad = lane >> 4, l16 = lane & 15;
  const int bh = blockIdx.y;
  const int b = bh >> 5, h = bh & 31, kh = h >> 2;
  const int qt = 31 - blockIdx.x;  // heavy blocks first
  const int ntiles = qt + 1;

  short8 qf[2];
#pragma unroll
  for (int c = 0; c < 2; c++)
    qf[c] = *(const short8*)(QKV +
        (size_t)(b * SEQ + qt * 64 + wave * 16 + l16) * QKV_LD +
        h * HDIM + c * 32 + quad * 8);

  f32x4 o[4] = {};
  float m = -INFINITY, l = 0.f;

  const ushort* Kbase = QKV + (size_t)b * SEQ * QKV_LD + 2048 + kh * HDIM;
  const ushort* Vbase = Kbase + 512;
  const int kp = tid & 31, dg = tid >> 5;
  const int relrow = wave * 16 + l16;

  for (int t = 0; t < ntiles; t++) {
    const int k0 = t * 64;
    __syncthreads();
    {
      const float4* kpp = (const float4*)(Kbase + (size_t)(k0 + lane) * QKV_LD + wave * 16);
      float4 kv0 = kpp[0], kv1 = kpp[1];
      const uint4* va4 = (const uint4*)(Vbase + (size_t)(k0 + 2 * kp) * QKV_LD + dg * 8);
      const uint4* vb4 = (const uint4*)(Vbase + (size_t)(k0 + 2 * kp + 1) * QKV_LD + dg * 8);
      uint4 va = va4[0], vb = vb4[0];
      *(float4*)&Ks[lane][wave * 16] = kv0;
      *(float4*)&Ks[lane][wave * 16 + 8] = kv1;
      const unsigned* vaw = (const unsigned*)&va;
      const unsigned* vbw = (const unsigned*)&vb;
#pragma unroll
      for (int j = 0; j < 8; j++) {
        unsigned pk = (j & 1)
            ? __builtin_amdgcn_perm(vbw[j >> 1], vaw[j >> 1], 0x07060302)
            : __builtin_amdgcn_perm(vbw[j >> 1], vaw[j >> 1], 0x05040100);
        *(unsigned*)&Vt[dg * 8 + j][2 * kp] = pk;
      }
    }
    __syncthreads();

    f32x4 s[4];
    __builtin_amdgcn_s_setprio(1);
#pragma unroll
    for (int nt = 0; nt < 4; nt++) {
      short8 kf0 = *(short8*)&Ks[nt * 16 + l16][quad * 8];
      short8 kf1 = *(short8*)&Ks[nt * 16 + l16][32 + quad * 8];
      f32x4 z = {};
      z = __builtin_amdgcn_mfma_f32_16x16x32_bf16(kf0, qf[0], z, 0, 0, 0);
      s[nt] = __builtin_amdgcn_mfma_f32_16x16x32_bf16(kf1, qf[1], z, 0, 0, 0);
    }
    __builtin_amdgcn_s_setprio(0);

    if (t == qt) {
#pragma unroll
      for (int nt = 0; nt < 4; nt++)
#pragma unroll
        for (int r = 0; r < 4; r++)
          if (nt * 16 + quad * 4 + r > relrow) s[nt][r] = -INFINITY;
    }

    float mx = s[0][0];
#pragma unroll
    for (int nt = 0; nt < 4; nt++)
#pragma unroll
      for (int r = 0; r < 4; r++) mx = fmaxf(mx, s[nt][r]);
    mx = fmaxf(mx, __shfl_xor(mx, 16));
    mx = fmaxf(mx, __shfl_xor(mx, 32));

    // T13 defer-max: only rescale when the tile max grows past the threshold
    if (!__all(mx <= m + 8.f)) {
      float mnew = fmaxf(m, mx);
      float al = hw_exp2(m - mnew);
      m = mnew;
      l *= al;
#pragma unroll
      for (int dt = 0; dt < 4; dt++)
#pragma unroll
        for (int r = 0; r < 4; r++) o[dt][r] *= al;
    }

    float psum = 0.f;
#pragma unroll
    for (int nt = 0; nt < 4; nt++) {
      float p0 = hw_exp2(s[nt][0] - m), p1 = hw_exp2(s[nt][1] - m);
      float p2 = hw_exp2(s[nt][2] - m), p3 = hw_exp2(s[nt][3] - m);
      psum += (p0 + p1) + (p2 + p3);
      unsigned lo = __builtin_amdgcn_perm(fbits(p1), fbits(p0), 0x07060302);
      unsigned hi = __builtin_amdgcn_perm(fbits(p3), fbits(p2), 0x07060302);
      uint2 pk; pk.x = lo; pk.y = hi;
      *(uint2*)&Pw[wave][l16][nt * 16 + quad * 4] = pk;
    }
    psum += __shfl_xor(psum, 16);
    psum += __shfl_xor(psum, 32);
    l += psum;

    short8 pf0 = *(short8*)&Pw[wave][l16][quad * 8];
    short8 pf1 = *(short8*)&Pw[wave][l16][32 + quad * 8];
    __builtin_amdgcn_s_setprio(1);
#pragma unroll
    for (int dt = 0; dt < 4; dt++) {
      short8 vf0 = *(short8*)&Vt[dt * 16 + l16][quad * 8];
      short8 vf1 = *(short8*)&Vt[dt * 16 + l16][32 + quad * 8];
      o[dt] = __builtin_amdgcn_mfma_f32_16x16x32_bf16(vf0, pf0, o[dt], 0, 0, 0);
      o[dt] = __builtin_amdgcn_mfma_f32_16x16x32_bf16(vf1, pf1, o[dt], 0, 0, 0);
    }
    __builtin_amdgcn_s_setprio(0);
  }

  {
    float inv = 1.0f / l;
    size_t rowg = (size_t)(b * SEQ + qt * 64 + wave * 16 + l16) * EMBED + h * HDIM;
#pragma unroll
    for (int dt = 0; dt < 4; dt++) {
      ushort q0 = f2bf(o[dt][0] * inv), q1 = f2bf(o[dt][1] * inv);
      ushort q2 = f2bf(o[dt][2] * inv), q3 = f2bf(o[dt][3] * inv);
      uint2 pk;
      pk.x = (unsigned)q0 | ((unsigned)q1 << 16);
      pk.y = (unsigned)q2 | ((unsigned)q3 << 16);
      *(uint2*)&O[rowg + dt * 16 + quad * 4] = pk;
    }
  }
}

// ---------------- launch ----------------
extern "C" void kernel_launch(void* const* d_in, const int* in_sizes, int n_in,
                              void* d_out, int out_size, void* d_ws, size_t ws_size,
                              hipStream_t stream) {
  const float* x = (const float*)d_in[0];
  const float* fcos = (const float*)d_in[1];
  const float* fsin = (const float*)d_in[2];
  const float* wq = (const float*)d_in[3];
  const float* wk = (const float*)d_in[4];
  const float* wv = (const float*)d_in[5];
  const float* wo = (const float*)d_in[6];
  float* out = (float*)d_out;

  const int M = BATCH * SEQ;  // 4096
  ushort* ws = (ushort*)d_ws;
  ushort* xb = ws;
  ushort* wqkv = xb + (size_t)M * EMBED;
  ushort* wob = wqkv + (size_t)QKV_LD * EMBED;
  ushort* QKVb = wob + (size_t)EMBED * EMBED;
  ushort* Ab = QKVb + (size_t)M * QKV_LD;

  dim3 blk(256);
  // all conversions in one launch: 18874368 elems / 8 per thread / 256
  cvt_all<<<9216, blk, 0, stream>>>(x, wq, wk, wv, wo, xb, wqkv, wob);

  gemm_bf16<ushort><<<dim3(QKV_LD / 128, M / 128), blk, 0, stream>>>(xb, wqkv, QKVb, M, QKV_LD, EMBED);

  {
    int tot = M * 40 * 4;  // 655360 threads, 16 dims per thread
    rope_qk<<<(tot + 255) / 256, blk, 0, stream>>>(QKVb, fcos, fsin, tot);
  }

  attn_mfma<<<dim3(32, BATCH * NHEADS), blk, 0, stream>>>(QKVb, Ab);

  gemm_bf16<float><<<dim3(EMBED / 128, M / 128), blk, 0, stream>>>(Ab, wob, out, M, EMBED, EMBED);
}

// Round 4
// 355.695 us; speedup vs baseline: 1.1082x; 1.1082x over previous
//
#include <hip/hip_runtime.h>

#define BATCH 2
#define SEQ 2048
#define EMBED 2048
#define NHEADS 32
#define NKV 8
#define HDIM 64
#define QKV_LD 3072  // fused [Q(2048) | K(512) | V(512)] row stride
#define LOG2E 1.44269504088896f

typedef __attribute__((ext_vector_type(8))) short short8;
typedef __attribute__((ext_vector_type(4))) float f32x4;

__device__ inline float hw_exp2(float x) { return __builtin_amdgcn_exp2f(x); }

__device__ inline ushort f2bf(float f) {
  union { float f; unsigned u; } v{f};
  unsigned r = v.u + 0x7FFF + ((v.u >> 16) & 1);
  return (ushort)(r >> 16);
}
__device__ inline float bf2f(ushort u) {
  union { unsigned u; float f; } v{((unsigned)u) << 16};
  return v.f;
}
__device__ inline unsigned fbits(float f) {
  union { float f; unsigned u; } v{f};
  return v.u;
}

__device__ inline void gload16(const ushort* g, ushort* l) {
  __builtin_amdgcn_global_load_lds(
      (const __attribute__((address_space(1))) unsigned*)g,
      (__attribute__((address_space(3))) unsigned*)l, 16, 0, 0);
}

// ---------------- fused fp32 -> bf16 convert (all 5 tensors, 1 launch) ----------------
// element ranges: x[0,8388608) wq[..12582912) wk[..13631488) wv[..14680064) wo[..18874368)
__global__ __launch_bounds__(256) void cvt_all(const float* __restrict__ x,
                                               const float* __restrict__ wq,
                                               const float* __restrict__ wk,
                                               const float* __restrict__ wv,
                                               const float* __restrict__ wo,
                                               ushort* __restrict__ xb,
                                               ushort* __restrict__ wqkv,
                                               ushort* __restrict__ wob) {
  size_t e = (size_t)(blockIdx.x * blockDim.x + threadIdx.x) * 8;
  const float* src;
  ushort* dst;
  if (e < 8388608u) { src = x + e; dst = xb + e; }
  else if (e < 12582912u) { size_t o = e - 8388608u; src = wq + o; dst = wqkv + o; }
  else if (e < 13631488u) { size_t o = e - 12582912u; src = wk + o; dst = wqkv + 4194304u + o; }
  else if (e < 14680064u) { size_t o = e - 13631488u; src = wv + o; dst = wqkv + 5242880u + o; }
  else { size_t o = e - 14680064u; src = wo + o; dst = wob + o; }
  float4 v0 = ((const float4*)src)[0];
  float4 v1 = ((const float4*)src)[1];
  union { uint4 v; ushort u[8]; } pk;
  pk.u[0] = f2bf(v0.x); pk.u[1] = f2bf(v0.y); pk.u[2] = f2bf(v0.z); pk.u[3] = f2bf(v0.w);
  pk.u[4] = f2bf(v1.x); pk.u[5] = f2bf(v1.y); pk.u[6] = f2bf(v1.z); pk.u[7] = f2bf(v1.w);
  *(uint4*)dst = pk.v;
}

// ---------------- bf16 MFMA GEMM (m97 structure): C[M,N] = A * B^T ----------------
template <typename OutT>
__global__ __launch_bounds__(256) void gemm_bf16(const ushort* __restrict__ A,
                                                 const ushort* __restrict__ B,
                                                 OutT* __restrict__ C,
                                                 int M, int N, int K) {
  __shared__ ushort As[128][32];
  __shared__ ushort Bs[128][32];
  const int tid = threadIdx.x;
  const int lane = tid & 63, wave = tid >> 6;
  const int quad = lane >> 4, l16 = lane & 15;
  const int m0 = blockIdx.y * 128, n0 = blockIdx.x * 128;
  const int wm = (wave >> 1) * 64, wn = (wave & 1) * 64;
  const int srow = lane >> 2, skq = (lane & 3) * 8;

  f32x4 acc[4][4] = {};
  for (int k0 = 0; k0 < K; k0 += 32) {
    const ushort* ga = A + (size_t)(m0 + wave * 32 + srow) * K + k0 + skq;
    const ushort* gb = B + (size_t)(n0 + wave * 32 + srow) * K + k0 + skq;
    __syncthreads();
    gload16(ga, &As[wave * 32][0]);
    gload16(ga + (size_t)16 * K, &As[wave * 32 + 16][0]);
    gload16(gb, &Bs[wave * 32][0]);
    gload16(gb + (size_t)16 * K, &Bs[wave * 32 + 16][0]);
    __syncthreads();
    short8 af[4], bf[4];
#pragma unroll
    for (int i = 0; i < 4; i++) af[i] = *(short8*)&As[wm + i * 16 + l16][quad * 8];
#pragma unroll
    for (int j = 0; j < 4; j++) bf[j] = *(short8*)&Bs[wn + j * 16 + l16][quad * 8];
#pragma unroll
    for (int i = 0; i < 4; i++)
#pragma unroll
      for (int j = 0; j < 4; j++)
        acc[i][j] = __builtin_amdgcn_mfma_f32_16x16x32_bf16(af[i], bf[j], acc[i][j], 0, 0, 0);
  }
#pragma unroll
  for (int i = 0; i < 4; i++) {
#pragma unroll
    for (int r = 0; r < 4; r++) {
      size_t rg = (size_t)(m0 + wm + i * 16 + quad * 4 + r);
#pragma unroll
      for (int j = 0; j < 4; j++) {
        float v = acc[i][j][r];
        int cg = n0 + wn + j * 16 + l16;
        if constexpr (sizeof(OutT) == 2)
          C[rg * N + cg] = f2bf(v);
        else
          C[rg * N + cg] = v;
      }
    }
  }
}

// ---------------- vectorized RoPE on fused QKV ----------------
// Q heads prescaled by 0.125*log2(e) (exp2-domain softmax downstream).
// thread = (tok, hh<40, g<4): handles dims [g*8, g*8+8) and [g*8+32, g*8+40).
__global__ __launch_bounds__(256) void rope_qk(ushort* __restrict__ t,
                                               const float* __restrict__ fc,
                                               const float* __restrict__ fs,
                                               int total) {
  int idx = blockIdx.x * blockDim.x + threadIdx.x;
  if (idx >= total) return;
  int g = idx & 3;
  int hh = (idx >> 2) % 40;
  int tok = idx / 160;
  int s = tok & (SEQ - 1);
  float scale = (hh < 32) ? 0.125f * LOG2E : 1.0f;
  ushort* p = t + (size_t)tok * QKV_LD + hh * 64 + g * 8;
  union { uint4 v; ushort u[8]; } lo, hi, olo, ohi;
  lo.v = *(const uint4*)p;
  hi.v = *(const uint4*)(p + 32);
  const float* fcb = fc + s * HDIM + g * 8;
  const float* fsb = fs + s * HDIM + g * 8;
  float4 c0a = ((const float4*)fcb)[0], c0b = ((const float4*)fcb)[1];
  float4 s0a = ((const float4*)fsb)[0], s0b = ((const float4*)fsb)[1];
  float4 c1a = ((const float4*)(fcb + 32))[0], c1b = ((const float4*)(fcb + 32))[1];
  float4 s1a = ((const float4*)(fsb + 32))[0], s1b = ((const float4*)(fsb + 32))[1];
  float cc0[8] = {c0a.x, c0a.y, c0a.z, c0a.w, c0b.x, c0b.y, c0b.z, c0b.w};
  float ss0[8] = {s0a.x, s0a.y, s0a.z, s0a.w, s0b.x, s0b.y, s0b.z, s0b.w};
  float cc1[8] = {c1a.x, c1a.y, c1a.z, c1a.w, c1b.x, c1b.y, c1b.z, c1b.w};
  float ss1[8] = {s1a.x, s1a.y, s1a.z, s1a.w, s1b.x, s1b.y, s1b.z, s1b.w};
#pragma unroll
  for (int j = 0; j < 8; j++) {
    float x0 = bf2f(lo.u[j]), x1 = bf2f(hi.u[j]);
    olo.u[j] = f2bf((x0 * cc0[j] - x1 * ss0[j]) * scale);
    ohi.u[j] = f2bf((x1 * cc1[j] + x0 * ss1[j]) * scale);
  }
  *(uint4*)p = olo.v;
  *(uint4*)(p + 32) = ohi.v;
}

// ---------------- MFMA flash attention v5 ----------------
// Contiguous 128-row q-block per block (vs v1's {p,31-p} pairing):
//  - same grid (16x64), same LDS (27.6KB), 4 blocks/CU;
//  - staging tiles per bh: 392 -> 272 (-30%) (causal range ends at own diagonal);
//  - each wave owns 2 contiguous 16-row frags; kf AND vf LDS reads shared
//    across both frags (one QK nt-loop, one PV dt-loop) -> ~40% fewer b128 reads;
//  - Pw per-wave buffer reused sequentially (P0 write/read then P1 write/read);
//  - T13 defer-max, T5 setprio.
__global__ __launch_bounds__(256, 4) void attn_mfma(const ushort* __restrict__ QKV,
                                                    ushort* __restrict__ O) {
  __shared__ ushort Ks[64][72];     // [key][d]
  __shared__ ushort Vt[64][72];     // [d][key]
  __shared__ ushort Pw[4][16][72];  // per-wave P[q][key], reused per frag
  const int tid = threadIdx.x;
  const int lane = tid & 63, wave = tid >> 6;
  const int quad = lane >> 4, l16 = lane & 15;
  const int bh = blockIdx.y;
  const int b = bh >> 5, h = bh & 31, kh = h >> 2;
  const int qblk = 15 - blockIdx.x;       // heavy blocks first
  const int ntiles = 2 * qblk + 2;        // causal K-range of this 128-row block
  const int wrow = qblk * 128 + wave * 32;  // this wave's first q row (global)

  // Q fragments: f=0 rows [wrow, wrow+16), f=1 rows [wrow+16, wrow+32)
  short8 qf[2][2];
#pragma unroll
  for (int f = 0; f < 2; f++)
#pragma unroll
    for (int c = 0; c < 2; c++)
      qf[f][c] = *(const short8*)(QKV +
          (size_t)(b * SEQ + wrow + f * 16 + l16) * QKV_LD +
          h * HDIM + c * 32 + quad * 8);

  f32x4 o[2][4] = {};
  float m[2] = {-INFINITY, -INFINITY}, l[2] = {0.f, 0.f};

  const ushort* Kbase = QKV + (size_t)b * SEQ * QKV_LD + 2048 + kh * HDIM;
  const ushort* Vbase = Kbase + 512;
  const int kp = tid & 31, dg = tid >> 5;

  for (int t = 0; t < ntiles; t++) {
    const int k0 = t * 64;
    __syncthreads();
    {
      const float4* kpp = (const float4*)(Kbase + (size_t)(k0 + lane) * QKV_LD + wave * 16);
      float4 kv0 = kpp[0], kv1 = kpp[1];
      const uint4* va4 = (const uint4*)(Vbase + (size_t)(k0 + 2 * kp) * QKV_LD + dg * 8);
      const uint4* vb4 = (const uint4*)(Vbase + (size_t)(k0 + 2 * kp + 1) * QKV_LD + dg * 8);
      uint4 va = va4[0], vb = vb4[0];
      *(float4*)&Ks[lane][wave * 16] = kv0;
      *(float4*)&Ks[lane][wave * 16 + 8] = kv1;
      const unsigned* vaw = (const unsigned*)&va;
      const unsigned* vbw = (const unsigned*)&vb;
#pragma unroll
      for (int j = 0; j < 8; j++) {
        unsigned pk = (j & 1)
            ? __builtin_amdgcn_perm(vbw[j >> 1], vaw[j >> 1], 0x07060302)
            : __builtin_amdgcn_perm(vbw[j >> 1], vaw[j >> 1], 0x05040100);
        *(unsigned*)&Vt[dg * 8 + j][2 * kp] = pk;
      }
    }
    __syncthreads();

    // wave fully below diagonal? (both frags fully masked -> only staging needed)
    if (k0 > wrow + 31) continue;
    const bool a0 = (k0 <= wrow + 15);  // frag 0 has any active keys

    // QK^T for both frags, kf shared
    f32x4 s0[4], s1[4];
    __builtin_amdgcn_s_setprio(1);
#pragma unroll
    for (int nt = 0; nt < 4; nt++) {
      short8 kf0 = *(short8*)&Ks[nt * 16 + l16][quad * 8];
      short8 kf1 = *(short8*)&Ks[nt * 16 + l16][32 + quad * 8];
      f32x4 z1 = {};
      z1 = __builtin_amdgcn_mfma_f32_16x16x32_bf16(kf0, qf[1][0], z1, 0, 0, 0);
      s1[nt] = __builtin_amdgcn_mfma_f32_16x16x32_bf16(kf1, qf[1][1], z1, 0, 0, 0);
      if (a0) {
        f32x4 z0 = {};
        z0 = __builtin_amdgcn_mfma_f32_16x16x32_bf16(kf0, qf[0][0], z0, 0, 0, 0);
        s0[nt] = __builtin_amdgcn_mfma_f32_16x16x32_bf16(kf1, qf[0][1], z0, 0, 0, 0);
      }
    }
    __builtin_amdgcn_s_setprio(0);

    // causal masking (diagonal region only)
    if (k0 + 63 > wrow + 16) {  // frag 1 diagonal
      const int lim1 = wrow + 16 + l16 - k0;
#pragma unroll
      for (int nt = 0; nt < 4; nt++)
#pragma unroll
        for (int r = 0; r < 4; r++)
          if (nt * 16 + quad * 4 + r > lim1) s1[nt][r] = -INFINITY;
    }
    if (a0 && k0 + 63 > wrow) {  // frag 0 diagonal
      const int lim0 = wrow + l16 - k0;
#pragma unroll
      for (int nt = 0; nt < 4; nt++)
#pragma unroll
        for (int r = 0; r < 4; r++)
          if (nt * 16 + quad * 4 + r > lim0) s0[nt][r] = -INFINITY;
    }

    // online softmax (T13 defer-max), Pw reused per frag
    auto smx = [&](f32x4 (&s)[4], float& mm, float& ll, f32x4 (&oo)[4]) {
      float mx = s[0][0];
#pragma unroll
      for (int nt = 0; nt < 4; nt++)
#pragma unroll
        for (int r = 0; r < 4; r++) mx = fmaxf(mx, s[nt][r]);
      mx = fmaxf(mx, __shfl_xor(mx, 16));
      mx = fmaxf(mx, __shfl_xor(mx, 32));
      if (!__all(mx <= mm + 8.f)) {
        float mnew = fmaxf(mm, mx);
        float al = hw_exp2(mm - mnew);
        mm = mnew;
        ll *= al;
#pragma unroll
        for (int dt = 0; dt < 4; dt++)
#pragma unroll
          for (int r = 0; r < 4; r++) oo[dt][r] *= al;
      }
      float psum = 0.f;
#pragma unroll
      for (int nt = 0; nt < 4; nt++) {
        float p0 = hw_exp2(s[nt][0] - mm), p1 = hw_exp2(s[nt][1] - mm);
        float p2 = hw_exp2(s[nt][2] - mm), p3 = hw_exp2(s[nt][3] - mm);
        psum += (p0 + p1) + (p2 + p3);
        unsigned lo = __builtin_amdgcn_perm(fbits(p1), fbits(p0), 0x07060302);
        unsigned hi = __builtin_amdgcn_perm(fbits(p3), fbits(p2), 0x07060302);
        uint2 pk; pk.x = lo; pk.y = hi;
        *(uint2*)&Pw[wave][l16][nt * 16 + quad * 4] = pk;
      }
      psum += __shfl_xor(psum, 16);
      psum += __shfl_xor(psum, 32);
      ll += psum;
    };

    short8 pf00, pf01, pf10, pf11;
    if (a0) {
      smx(s0, m[0], l[0], o[0]);
      pf00 = *(short8*)&Pw[wave][l16][quad * 8];
      pf01 = *(short8*)&Pw[wave][l16][32 + quad * 8];
    }
    smx(s1, m[1], l[1], o[1]);
    pf10 = *(short8*)&Pw[wave][l16][quad * 8];
    pf11 = *(short8*)&Pw[wave][l16][32 + quad * 8];

    // PV for both frags, vf shared
    __builtin_amdgcn_s_setprio(1);
#pragma unroll
    for (int dt = 0; dt < 4; dt++) {
      short8 vf0 = *(short8*)&Vt[dt * 16 + l16][quad * 8];
      short8 vf1 = *(short8*)&Vt[dt * 16 + l16][32 + quad * 8];
      o[1][dt] = __builtin_amdgcn_mfma_f32_16x16x32_bf16(vf0, pf10, o[1][dt], 0, 0, 0);
      o[1][dt] = __builtin_amdgcn_mfma_f32_16x16x32_bf16(vf1, pf11, o[1][dt], 0, 0, 0);
      if (a0) {
        o[0][dt] = __builtin_amdgcn_mfma_f32_16x16x32_bf16(vf0, pf00, o[0][dt], 0, 0, 0);
        o[0][dt] = __builtin_amdgcn_mfma_f32_16x16x32_bf16(vf1, pf01, o[0][dt], 0, 0, 0);
      }
    }
    __builtin_amdgcn_s_setprio(0);
  }

#pragma unroll
  for (int f = 0; f < 2; f++) {
    float inv = 1.0f / l[f];
    size_t rowg = (size_t)(b * SEQ + wrow + f * 16 + l16) * EMBED + h * HDIM;
#pragma unroll
    for (int dt = 0; dt < 4; dt++) {
      ushort q0 = f2bf(o[f][dt][0] * inv), q1 = f2bf(o[f][dt][1] * inv);
      ushort q2 = f2bf(o[f][dt][2] * inv), q3 = f2bf(o[f][dt][3] * inv);
      uint2 pk;
      pk.x = (unsigned)q0 | ((unsigned)q1 << 16);
      pk.y = (unsigned)q2 | ((unsigned)q3 << 16);
      *(uint2*)&O[rowg + dt * 16 + quad * 4] = pk;
    }
  }
}

// ---------------- launch ----------------
extern "C" void kernel_launch(void* const* d_in, const int* in_sizes, int n_in,
                              void* d_out, int out_size, void* d_ws, size_t ws_size,
                              hipStream_t stream) {
  const float* x = (const float*)d_in[0];
  const float* fcos = (const float*)d_in[1];
  const float* fsin = (const float*)d_in[2];
  const float* wq = (const float*)d_in[3];
  const float* wk = (const float*)d_in[4];
  const float* wv = (const float*)d_in[5];
  const float* wo = (const float*)d_in[6];
  float* out = (float*)d_out;

  const int M = BATCH * SEQ;  // 4096
  ushort* ws = (ushort*)d_ws;
  ushort* xb = ws;
  ushort* wqkv = xb + (size_t)M * EMBED;
  ushort* wob = wqkv + (size_t)QKV_LD * EMBED;
  ushort* QKVb = wob + (size_t)EMBED * EMBED;
  ushort* Ab = QKVb + (size_t)M * QKV_LD;

  dim3 blk(256);
  // all conversions in one launch: 18874368 elems / 8 per thread / 256
  cvt_all<<<9216, blk, 0, stream>>>(x, wq, wk, wv, wo, xb, wqkv, wob);

  gemm_bf16<ushort><<<dim3(QKV_LD / 128, M / 128), blk, 0, stream>>>(xb, wqkv, QKVb, M, QKV_LD, EMBED);

  {
    int tot = M * 40 * 4;  // 655360 threads, 16 dims per thread
    rope_qk<<<(tot + 255) / 256, blk, 0, stream>>>(QKVb, fcos, fsin, tot);
  }

  attn_mfma<<<dim3(16, BATCH * NHEADS), blk, 0, stream>>>(QKVb, Ab);

  gemm_bf16<float><<<dim3(EMBED / 128, M / 128), blk, 0, stream>>>(Ab, wob, out, M, EMBED, EMBED);
}

// Round 5
// 338.381 us; speedup vs baseline: 1.1649x; 1.0512x over previous
//
#include <hip/hip_runtime.h>

#define BATCH 2
#define SEQ 2048
#define EMBED 2048
#define NHEADS 32
#define NKV 8
#define HDIM 64
#define QKV_LD 3072  // fused [Q(2048) | K(512) | V(512)] row stride
#define LOG2E 1.44269504088896f

typedef __attribute__((ext_vector_type(8))) short short8;
typedef __attribute__((ext_vector_type(4))) float f32x4;

__device__ inline float hw_exp2(float x) { return __builtin_amdgcn_exp2f(x); }

__device__ inline ushort f2bf(float f) {
  union { float f; unsigned u; } v{f};
  unsigned r = v.u + 0x7FFF + ((v.u >> 16) & 1);
  return (ushort)(r >> 16);
}
__device__ inline float bf2f(ushort u) {
  union { unsigned u; float f; } v{((unsigned)u) << 16};
  return v.f;
}
__device__ inline unsigned fbits(float f) {
  union { float f; unsigned u; } v{f};
  return v.u;
}

__device__ inline void gload16(const ushort* g, ushort* l) {
  __builtin_amdgcn_global_load_lds(
      (const __attribute__((address_space(1))) unsigned*)g,
      (__attribute__((address_space(3))) unsigned*)l, 16, 0, 0);
}

// ---------------- fused fp32 -> bf16 convert (all 5 tensors, 1 launch) ----------------
// element ranges: x[0,8388608) wq[..12582912) wk[..13631488) wv[..14680064) wo[..18874368)
__global__ __launch_bounds__(256) void cvt_all(const float* __restrict__ x,
                                               const float* __restrict__ wq,
                                               const float* __restrict__ wk,
                                               const float* __restrict__ wv,
                                               const float* __restrict__ wo,
                                               ushort* __restrict__ xb,
                                               ushort* __restrict__ wqkv,
                                               ushort* __restrict__ wob) {
  size_t e = (size_t)(blockIdx.x * blockDim.x + threadIdx.x) * 8;
  const float* src;
  ushort* dst;
  if (e < 8388608u) { src = x + e; dst = xb + e; }
  else if (e < 12582912u) { size_t o = e - 8388608u; src = wq + o; dst = wqkv + o; }
  else if (e < 13631488u) { size_t o = e - 12582912u; src = wk + o; dst = wqkv + 4194304u + o; }
  else if (e < 14680064u) { size_t o = e - 13631488u; src = wv + o; dst = wqkv + 5242880u + o; }
  else { size_t o = e - 14680064u; src = wo + o; dst = wob + o; }
  float4 v0 = ((const float4*)src)[0];
  float4 v1 = ((const float4*)src)[1];
  union { uint4 v; ushort u[8]; } pk;
  pk.u[0] = f2bf(v0.x); pk.u[1] = f2bf(v0.y); pk.u[2] = f2bf(v0.z); pk.u[3] = f2bf(v0.w);
  pk.u[4] = f2bf(v1.x); pk.u[5] = f2bf(v1.y); pk.u[6] = f2bf(v1.z); pk.u[7] = f2bf(v1.w);
  *(uint4*)dst = pk.v;
}

// ---------------- bf16 MFMA GEMM (m97 structure): C[M,N] = A * B^T ----------------
template <typename OutT>
__global__ __launch_bounds__(256) void gemm_bf16(const ushort* __restrict__ A,
                                                 const ushort* __restrict__ B,
                                                 OutT* __restrict__ C,
                                                 int M, int N, int K) {
  __shared__ ushort As[128][32];
  __shared__ ushort Bs[128][32];
  const int tid = threadIdx.x;
  const int lane = tid & 63, wave = tid >> 6;
  const int quad = lane >> 4, l16 = lane & 15;
  const int m0 = blockIdx.y * 128, n0 = blockIdx.x * 128;
  const int wm = (wave >> 1) * 64, wn = (wave & 1) * 64;
  const int srow = lane >> 2, skq = (lane & 3) * 8;

  f32x4 acc[4][4] = {};
  for (int k0 = 0; k0 < K; k0 += 32) {
    const ushort* ga = A + (size_t)(m0 + wave * 32 + srow) * K + k0 + skq;
    const ushort* gb = B + (size_t)(n0 + wave * 32 + srow) * K + k0 + skq;
    __syncthreads();
    gload16(ga, &As[wave * 32][0]);
    gload16(ga + (size_t)16 * K, &As[wave * 32 + 16][0]);
    gload16(gb, &Bs[wave * 32][0]);
    gload16(gb + (size_t)16 * K, &Bs[wave * 32 + 16][0]);
    __syncthreads();
    short8 af[4], bf[4];
#pragma unroll
    for (int i = 0; i < 4; i++) af[i] = *(short8*)&As[wm + i * 16 + l16][quad * 8];
#pragma unroll
    for (int j = 0; j < 4; j++) bf[j] = *(short8*)&Bs[wn + j * 16 + l16][quad * 8];
#pragma unroll
    for (int i = 0; i < 4; i++)
#pragma unroll
      for (int j = 0; j < 4; j++)
        acc[i][j] = __builtin_amdgcn_mfma_f32_16x16x32_bf16(af[i], bf[j], acc[i][j], 0, 0, 0);
  }
#pragma unroll
  for (int i = 0; i < 4; i++) {
#pragma unroll
    for (int r = 0; r < 4; r++) {
      size_t rg = (size_t)(m0 + wm + i * 16 + quad * 4 + r);
#pragma unroll
      for (int j = 0; j < 4; j++) {
        float v = acc[i][j][r];
        int cg = n0 + wn + j * 16 + l16;
        if constexpr (sizeof(OutT) == 2)
          C[rg * N + cg] = f2bf(v);
        else
          C[rg * N + cg] = v;
      }
    }
  }
}

// ---------------- vectorized RoPE on fused QKV ----------------
// Q heads prescaled by 0.125*log2(e) (exp2-domain softmax downstream).
// thread = (tok, hh<40, g<4): handles dims [g*8, g*8+8) and [g*8+32, g*8+40).
__global__ __launch_bounds__(256) void rope_qk(ushort* __restrict__ t,
                                               const float* __restrict__ fc,
                                               const float* __restrict__ fs,
                                               int total) {
  int idx = blockIdx.x * blockDim.x + threadIdx.x;
  if (idx >= total) return;
  int g = idx & 3;
  int hh = (idx >> 2) % 40;
  int tok = idx / 160;
  int s = tok & (SEQ - 1);
  float scale = (hh < 32) ? 0.125f * LOG2E : 1.0f;
  ushort* p = t + (size_t)tok * QKV_LD + hh * 64 + g * 8;
  union { uint4 v; ushort u[8]; } lo, hi, olo, ohi;
  lo.v = *(const uint4*)p;
  hi.v = *(const uint4*)(p + 32);
  const float* fcb = fc + s * HDIM + g * 8;
  const float* fsb = fs + s * HDIM + g * 8;
  float4 c0a = ((const float4*)fcb)[0], c0b = ((const float4*)fcb)[1];
  float4 s0a = ((const float4*)fsb)[0], s0b = ((const float4*)fsb)[1];
  float4 c1a = ((const float4*)(fcb + 32))[0], c1b = ((const float4*)(fcb + 32))[1];
  float4 s1a = ((const float4*)(fsb + 32))[0], s1b = ((const float4*)(fsb + 32))[1];
  float cc0[8] = {c0a.x, c0a.y, c0a.z, c0a.w, c0b.x, c0b.y, c0b.z, c0b.w};
  float ss0[8] = {s0a.x, s0a.y, s0a.z, s0a.w, s0b.x, s0b.y, s0b.z, s0b.w};
  float cc1[8] = {c1a.x, c1a.y, c1a.z, c1a.w, c1b.x, c1b.y, c1b.z, c1b.w};
  float ss1[8] = {s1a.x, s1a.y, s1a.z, s1a.w, s1b.x, s1b.y, s1b.z, s1b.w};
#pragma unroll
  for (int j = 0; j < 8; j++) {
    float x0 = bf2f(lo.u[j]), x1 = bf2f(hi.u[j]);
    olo.u[j] = f2bf((x0 * cc0[j] - x1 * ss0[j]) * scale);
    ohi.u[j] = f2bf((x1 * cc1[j] + x0 * ss1[j]) * scale);
  }
  *(uint4*)p = olo.v;
  *(uint4*)(p + 32) = ohi.v;
}

// ---------------- MFMA flash attention v6 ----------------
// v5 body (contiguous 128-row q-block, shared kf/vf, T13, T5) with a
// CU-BALANCED block mapping:
//  - MI355X assigns CU by bid%256 (XCD=bid%8, CU=(bid>>3)%32); with 1024
//    blocks all resident (4/CU), a CU holds bids {c, c+256, c+512, c+768}.
//  - mapping qq=bid>>8, j=(bid>>6)&3, bh=bid&63,
//    qblk = (qq>>1)*8 + (qq&1 ? 7-j : j)
//    gives each CU qblks {j, 7-j, 8+j, 15-j}: per-CU staging-tile sum = 68
//    for EVERY CU (v5's dim3(16,64) gave each CU 4 blocks of the SAME qblk,
//    a 16x work spread -> 112us despite less total work).
__global__ __launch_bounds__(256, 4) void attn_mfma(const ushort* __restrict__ QKV,
                                                    ushort* __restrict__ O) {
  __shared__ ushort Ks[64][72];     // [key][d]
  __shared__ ushort Vt[64][72];     // [d][key]
  __shared__ ushort Pw[4][16][72];  // per-wave P[q][key], reused per frag
  const int tid = threadIdx.x;
  const int lane = tid & 63, wave = tid >> 6;
  const int quad = lane >> 4, l16 = lane & 15;

  // CU-balanced (qblk, bh) derivation
  const int bid = blockIdx.x;
  const int qq = bid >> 8;         // quarter 0..3
  const int j4 = (bid >> 6) & 3;   // 0..3
  const int bh = bid & 63;
  const int qblk = (qq >> 1) * 8 + ((qq & 1) ? 7 - j4 : j4);

  const int b = bh >> 5, h = bh & 31, kh = h >> 2;
  const int ntiles = 2 * qblk + 2;          // causal K-range of this 128-row block
  const int wrow = qblk * 128 + wave * 32;  // this wave's first q row (global)

  // Q fragments: f=0 rows [wrow, wrow+16), f=1 rows [wrow+16, wrow+32)
  short8 qf[2][2];
#pragma unroll
  for (int f = 0; f < 2; f++)
#pragma unroll
    for (int c = 0; c < 2; c++)
      qf[f][c] = *(const short8*)(QKV +
          (size_t)(b * SEQ + wrow + f * 16 + l16) * QKV_LD +
          h * HDIM + c * 32 + quad * 8);

  f32x4 o[2][4] = {};
  float m[2] = {-INFINITY, -INFINITY}, l[2] = {0.f, 0.f};

  const ushort* Kbase = QKV + (size_t)b * SEQ * QKV_LD + 2048 + kh * HDIM;
  const ushort* Vbase = Kbase + 512;
  const int kp = tid & 31, dg = tid >> 5;

  for (int t = 0; t < ntiles; t++) {
    const int k0 = t * 64;
    __syncthreads();
    {
      const float4* kpp = (const float4*)(Kbase + (size_t)(k0 + lane) * QKV_LD + wave * 16);
      float4 kv0 = kpp[0], kv1 = kpp[1];
      const uint4* va4 = (const uint4*)(Vbase + (size_t)(k0 + 2 * kp) * QKV_LD + dg * 8);
      const uint4* vb4 = (const uint4*)(Vbase + (size_t)(k0 + 2 * kp + 1) * QKV_LD + dg * 8);
      uint4 va = va4[0], vb = vb4[0];
      *(float4*)&Ks[lane][wave * 16] = kv0;
      *(float4*)&Ks[lane][wave * 16 + 8] = kv1;
      const unsigned* vaw = (const unsigned*)&va;
      const unsigned* vbw = (const unsigned*)&vb;
#pragma unroll
      for (int j = 0; j < 8; j++) {
        unsigned pk = (j & 1)
            ? __builtin_amdgcn_perm(vbw[j >> 1], vaw[j >> 1], 0x07060302)
            : __builtin_amdgcn_perm(vbw[j >> 1], vaw[j >> 1], 0x05040100);
        *(unsigned*)&Vt[dg * 8 + j][2 * kp] = pk;
      }
    }
    __syncthreads();

    // wave fully below diagonal? (both frags fully masked -> only staging needed)
    if (k0 > wrow + 31) continue;
    const bool a0 = (k0 <= wrow + 15);  // frag 0 has any active keys

    // QK^T for both frags, kf shared
    f32x4 s0[4], s1[4];
    __builtin_amdgcn_s_setprio(1);
#pragma unroll
    for (int nt = 0; nt < 4; nt++) {
      short8 kf0 = *(short8*)&Ks[nt * 16 + l16][quad * 8];
      short8 kf1 = *(short8*)&Ks[nt * 16 + l16][32 + quad * 8];
      f32x4 z1 = {};
      z1 = __builtin_amdgcn_mfma_f32_16x16x32_bf16(kf0, qf[1][0], z1, 0, 0, 0);
      s1[nt] = __builtin_amdgcn_mfma_f32_16x16x32_bf16(kf1, qf[1][1], z1, 0, 0, 0);
      if (a0) {
        f32x4 z0 = {};
        z0 = __builtin_amdgcn_mfma_f32_16x16x32_bf16(kf0, qf[0][0], z0, 0, 0, 0);
        s0[nt] = __builtin_amdgcn_mfma_f32_16x16x32_bf16(kf1, qf[0][1], z0, 0, 0, 0);
      }
    }
    __builtin_amdgcn_s_setprio(0);

    // causal masking (diagonal region only)
    if (k0 + 63 > wrow + 16) {  // frag 1 diagonal
      const int lim1 = wrow + 16 + l16 - k0;
#pragma unroll
      for (int nt = 0; nt < 4; nt++)
#pragma unroll
        for (int r = 0; r < 4; r++)
          if (nt * 16 + quad * 4 + r > lim1) s1[nt][r] = -INFINITY;
    }
    if (a0 && k0 + 63 > wrow) {  // frag 0 diagonal
      const int lim0 = wrow + l16 - k0;
#pragma unroll
      for (int nt = 0; nt < 4; nt++)
#pragma unroll
        for (int r = 0; r < 4; r++)
          if (nt * 16 + quad * 4 + r > lim0) s0[nt][r] = -INFINITY;
    }

    // online softmax (T13 defer-max), Pw reused per frag
    auto smx = [&](f32x4 (&s)[4], float& mm, float& ll, f32x4 (&oo)[4]) {
      float mx = s[0][0];
#pragma unroll
      for (int nt = 0; nt < 4; nt++)
#pragma unroll
        for (int r = 0; r < 4; r++) mx = fmaxf(mx, s[nt][r]);
      mx = fmaxf(mx, __shfl_xor(mx, 16));
      mx = fmaxf(mx, __shfl_xor(mx, 32));
      if (!__all(mx <= mm + 8.f)) {
        float mnew = fmaxf(mm, mx);
        float al = hw_exp2(mm - mnew);
        mm = mnew;
        ll *= al;
#pragma unroll
        for (int dt = 0; dt < 4; dt++)
#pragma unroll
          for (int r = 0; r < 4; r++) oo[dt][r] *= al;
      }
      float psum = 0.f;
#pragma unroll
      for (int nt = 0; nt < 4; nt++) {
        float p0 = hw_exp2(s[nt][0] - mm), p1 = hw_exp2(s[nt][1] - mm);
        float p2 = hw_exp2(s[nt][2] - mm), p3 = hw_exp2(s[nt][3] - mm);
        psum += (p0 + p1) + (p2 + p3);
        unsigned lo = __builtin_amdgcn_perm(fbits(p1), fbits(p0), 0x07060302);
        unsigned hi = __builtin_amdgcn_perm(fbits(p3), fbits(p2), 0x07060302);
        uint2 pk; pk.x = lo; pk.y = hi;
        *(uint2*)&Pw[wave][l16][nt * 16 + quad * 4] = pk;
      }
      psum += __shfl_xor(psum, 16);
      psum += __shfl_xor(psum, 32);
      ll += psum;
    };

    short8 pf00, pf01, pf10, pf11;
    if (a0) {
      smx(s0, m[0], l[0], o[0]);
      pf00 = *(short8*)&Pw[wave][l16][quad * 8];
      pf01 = *(short8*)&Pw[wave][l16][32 + quad * 8];
    }
    smx(s1, m[1], l[1], o[1]);
    pf10 = *(short8*)&Pw[wave][l16][quad * 8];
    pf11 = *(short8*)&Pw[wave][l16][32 + quad * 8];

    // PV for both frags, vf shared
    __builtin_amdgcn_s_setprio(1);
#pragma unroll
    for (int dt = 0; dt < 4; dt++) {
      short8 vf0 = *(short8*)&Vt[dt * 16 + l16][quad * 8];
      short8 vf1 = *(short8*)&Vt[dt * 16 + l16][32 + quad * 8];
      o[1][dt] = __builtin_amdgcn_mfma_f32_16x16x32_bf16(vf0, pf10, o[1][dt], 0, 0, 0);
      o[1][dt] = __builtin_amdgcn_mfma_f32_16x16x32_bf16(vf1, pf11, o[1][dt], 0, 0, 0);
      if (a0) {
        o[0][dt] = __builtin_amdgcn_mfma_f32_16x16x32_bf16(vf0, pf00, o[0][dt], 0, 0, 0);
        o[0][dt] = __builtin_amdgcn_mfma_f32_16x16x32_bf16(vf1, pf01, o[0][dt], 0, 0, 0);
      }
    }
    __builtin_amdgcn_s_setprio(0);
  }

#pragma unroll
  for (int f = 0; f < 2; f++) {
    float inv = 1.0f / l[f];
    size_t rowg = (size_t)(b * SEQ + wrow + f * 16 + l16) * EMBED + h * HDIM;
#pragma unroll
    for (int dt = 0; dt < 4; dt++) {
      ushort q0 = f2bf(o[f][dt][0] * inv), q1 = f2bf(o[f][dt][1] * inv);
      ushort q2 = f2bf(o[f][dt][2] * inv), q3 = f2bf(o[f][dt][3] * inv);
      uint2 pk;
      pk.x = (unsigned)q0 | ((unsigned)q1 << 16);
      pk.y = (unsigned)q2 | ((unsigned)q3 << 16);
      *(uint2*)&O[rowg + dt * 16 + quad * 4] = pk;
    }
  }
}

// ---------------- launch ----------------
extern "C" void kernel_launch(void* const* d_in, const int* in_sizes, int n_in,
                              void* d_out, int out_size, void* d_ws, size_t ws_size,
                              hipStream_t stream) {
  const float* x = (const float*)d_in[0];
  const float* fcos = (const float*)d_in[1];
  const float* fsin = (const float*)d_in[2];
  const float* wq = (const float*)d_in[3];
  const float* wk = (const float*)d_in[4];
  const float* wv = (const float*)d_in[5];
  const float* wo = (const float*)d_in[6];
  float* out = (float*)d_out;

  const int M = BATCH * SEQ;  // 4096
  ushort* ws = (ushort*)d_ws;
  ushort* xb = ws;
  ushort* wqkv = xb + (size_t)M * EMBED;
  ushort* wob = wqkv + (size_t)QKV_LD * EMBED;
  ushort* QKVb = wob + (size_t)EMBED * EMBED;
  ushort* Ab = QKVb + (size_t)M * QKV_LD;

  dim3 blk(256);
  // all conversions in one launch: 18874368 elems / 8 per thread / 256
  cvt_all<<<9216, blk, 0, stream>>>(x, wq, wk, wv, wo, xb, wqkv, wob);

  gemm_bf16<ushort><<<dim3(QKV_LD / 128, M / 128), blk, 0, stream>>>(xb, wqkv, QKVb, M, QKV_LD, EMBED);

  {
    int tot = M * 40 * 4;  // 655360 threads, 16 dims per thread
    rope_qk<<<(tot + 255) / 256, blk, 0, stream>>>(QKVb, fcos, fsin, tot);
  }

  attn_mfma<<<dim3(1024), blk, 0, stream>>>(QKVb, Ab);

  gemm_bf16<float><<<dim3(EMBED / 128, M / 128), blk, 0, stream>>>(Ab, wob, out, M, EMBED, EMBED);
}

// Round 6
// 322.250 us; speedup vs baseline: 1.2232x; 1.0501x over previous
//
#include <hip/hip_runtime.h>

#define BATCH 2
#define SEQ 2048
#define EMBED 2048
#define NHEADS 32
#define NKV 8
#define HDIM 64
#define QKV_LD 3072  // fused [Q(2048) | K(512) | V(512)] row stride
#define LOG2E 1.44269504088896f

typedef __attribute__((ext_vector_type(8))) short short8;
typedef __attribute__((ext_vector_type(4))) float f32x4;

__device__ inline float hw_exp2(float x) { return __builtin_amdgcn_exp2f(x); }

__device__ inline ushort f2bf(float f) {
  union { float f; unsigned u; } v{f};
  unsigned r = v.u + 0x7FFF + ((v.u >> 16) & 1);
  return (ushort)(r >> 16);
}
__device__ inline float bf2f(ushort u) {
  union { unsigned u; float f; } v{((unsigned)u) << 16};
  return v.f;
}
__device__ inline unsigned fbits(float f) {
  union { float f; unsigned u; } v{f};
  return v.u;
}

__device__ inline void gload16(const ushort* g, ushort* l) {
  __builtin_amdgcn_global_load_lds(
      (const __attribute__((address_space(1))) unsigned*)g,
      (__attribute__((address_space(3))) unsigned*)l, 16, 0, 0);
}

#define PHASE_BAR()                          \
  do {                                       \
    __builtin_amdgcn_sched_barrier(0);       \
    __builtin_amdgcn_s_barrier();            \
    __builtin_amdgcn_sched_barrier(0);       \
  } while (0)

// ---------------- fused fp32 -> bf16 convert (all 5 tensors, 1 launch) ----------------
// element ranges: x[0,8388608) wq[..12582912) wk[..13631488) wv[..14680064) wo[..18874368)
__global__ __launch_bounds__(256) void cvt_all(const float* __restrict__ x,
                                               const float* __restrict__ wq,
                                               const float* __restrict__ wk,
                                               const float* __restrict__ wv,
                                               const float* __restrict__ wo,
                                               ushort* __restrict__ xb,
                                               ushort* __restrict__ wqkv,
                                               ushort* __restrict__ wob) {
  size_t e = (size_t)(blockIdx.x * blockDim.x + threadIdx.x) * 8;
  const float* src;
  ushort* dst;
  if (e < 8388608u) { src = x + e; dst = xb + e; }
  else if (e < 12582912u) { size_t o = e - 8388608u; src = wq + o; dst = wqkv + o; }
  else if (e < 13631488u) { size_t o = e - 12582912u; src = wk + o; dst = wqkv + 4194304u + o; }
  else if (e < 14680064u) { size_t o = e - 13631488u; src = wv + o; dst = wqkv + 5242880u + o; }
  else { size_t o = e - 14680064u; src = wo + o; dst = wob + o; }
  float4 v0 = ((const float4*)src)[0];
  float4 v1 = ((const float4*)src)[1];
  union { uint4 v; ushort u[8]; } pk;
  pk.u[0] = f2bf(v0.x); pk.u[1] = f2bf(v0.y); pk.u[2] = f2bf(v0.z); pk.u[3] = f2bf(v0.w);
  pk.u[4] = f2bf(v1.x); pk.u[5] = f2bf(v1.y); pk.u[6] = f2bf(v1.z); pk.u[7] = f2bf(v1.w);
  *(uint4*)dst = pk.v;
}

// ---------------- bf16 MFMA GEMM (m97 structure): C[M,N] = A * B^T ----------------
template <typename OutT>
__global__ __launch_bounds__(256) void gemm_bf16(const ushort* __restrict__ A,
                                                 const ushort* __restrict__ B,
                                                 OutT* __restrict__ C,
                                                 int M, int N, int K) {
  __shared__ ushort As[128][32];
  __shared__ ushort Bs[128][32];
  const int tid = threadIdx.x;
  const int lane = tid & 63, wave = tid >> 6;
  const int quad = lane >> 4, l16 = lane & 15;
  const int m0 = blockIdx.y * 128, n0 = blockIdx.x * 128;
  const int wm = (wave >> 1) * 64, wn = (wave & 1) * 64;
  const int srow = lane >> 2, skq = (lane & 3) * 8;

  f32x4 acc[4][4] = {};
  for (int k0 = 0; k0 < K; k0 += 32) {
    const ushort* ga = A + (size_t)(m0 + wave * 32 + srow) * K + k0 + skq;
    const ushort* gb = B + (size_t)(n0 + wave * 32 + srow) * K + k0 + skq;
    __syncthreads();
    gload16(ga, &As[wave * 32][0]);
    gload16(ga + (size_t)16 * K, &As[wave * 32 + 16][0]);
    gload16(gb, &Bs[wave * 32][0]);
    gload16(gb + (size_t)16 * K, &Bs[wave * 32 + 16][0]);
    __syncthreads();
    short8 af[4], bf[4];
#pragma unroll
    for (int i = 0; i < 4; i++) af[i] = *(short8*)&As[wm + i * 16 + l16][quad * 8];
#pragma unroll
    for (int j = 0; j < 4; j++) bf[j] = *(short8*)&Bs[wn + j * 16 + l16][quad * 8];
#pragma unroll
    for (int i = 0; i < 4; i++)
#pragma unroll
      for (int j = 0; j < 4; j++)
        acc[i][j] = __builtin_amdgcn_mfma_f32_16x16x32_bf16(af[i], bf[j], acc[i][j], 0, 0, 0);
  }
#pragma unroll
  for (int i = 0; i < 4; i++) {
#pragma unroll
    for (int r = 0; r < 4; r++) {
      size_t rg = (size_t)(m0 + wm + i * 16 + quad * 4 + r);
#pragma unroll
      for (int j = 0; j < 4; j++) {
        float v = acc[i][j][r];
        int cg = n0 + wn + j * 16 + l16;
        if constexpr (sizeof(OutT) == 2)
          C[rg * N + cg] = f2bf(v);
        else
          C[rg * N + cg] = v;
      }
    }
  }
}

// ---------------- 256x256 8-phase bf16 GEMM (m201-class, kk-split banking) ----------
// C[M,N] = A * B^T. 512 threads = 8 waves (2M x 4N), per-wave output 128x64.
// LDS: A,B each [2 buf][2 kk][256 rows][32] bf16 = 64KB+64KB = 128KB.
//   - 64B rows reproduce m97's conflict-free fragment banking (no XOR swizzle
//     needed) while keeping global_load_lds destinations linear (m104-safe).
// Per K-tile T (BK=64): 4 phases x 16 MFMA. B-frags read once (phase 0), A-frags
// per phase. Phase q stages one half-tile of T+1 into the OTHER buffer
// (q0:A0,q1:A1,q2:B0,q3:B1) -> no intra-tile WAR; the only WAR (A/B of T-1 vs
// stage of T+1) is barrier-separated. vmcnt(0) once per K-tile at the top:
// T's loads were issued 1-4 phases earlier, latency hidden under MFMA.
__global__ __launch_bounds__(512) void gemm8p(const ushort* __restrict__ Ag,
                                              const ushort* __restrict__ Bg,
                                              ushort* __restrict__ C,
                                              int M, int N, int K) {
  __shared__ ushort As[2][2][256][32];
  __shared__ ushort Bs[2][2][256][32];
  const int tid = threadIdx.x;
  const int lane = tid & 63, wave = tid >> 6;
  const int quad = lane >> 4, l16 = lane & 15;
  const int wm = wave >> 2, wn = wave & 3;  // 2M x 4N
  const int m0 = blockIdx.y * 256, n0 = blockIdx.x * 256;
  const int NT = K >> 6;

  // stage helpers: one half-tile (128 rows) -> this wave covers 16 rows,
  // 2 gload16 calls (one per kk subtile). LDS dest wave-uniform; source per-lane.
  auto stA = [&](int Tn, int h) {
    const int r0 = h * 128 + wave * 16;
    const ushort* g = Ag + (size_t)(m0 + r0 + (lane >> 2)) * K + Tn * 64 + (lane & 3) * 8;
    gload16(g, &As[Tn & 1][0][r0][0]);
    gload16(g + 32, &As[Tn & 1][1][r0][0]);
  };
  auto stB = [&](int Tn, int h) {
    const int r0 = h * 128 + wave * 16;
    const ushort* g = Bg + (size_t)(n0 + r0 + (lane >> 2)) * K + Tn * 64 + (lane & 3) * 8;
    gload16(g, &Bs[Tn & 1][0][r0][0]);
    gload16(g + 32, &Bs[Tn & 1][1][r0][0]);
  };

  f32x4 acc[8][4] = {};

  // prologue: stage K-tile 0 fully
  stA(0, 0); stA(0, 1); stB(0, 0); stB(0, 1);

  for (int T = 0; T < NT; ++T) {
    const int bf = T & 1;
    asm volatile("s_waitcnt vmcnt(0)" ::: "memory");
    PHASE_BAR();

    // B-frags for the whole K-tile (phase 0 reads)
    short8 bfr[4][2];
#pragma unroll
    for (int nf = 0; nf < 4; nf++)
#pragma unroll
      for (int kk = 0; kk < 2; kk++)
        bfr[nf][kk] = *(short8*)&Bs[bf][kk][wn * 64 + nf * 16 + l16][quad * 8];

#pragma unroll
    for (int q = 0; q < 4; q++) {
      short8 afr[2][2];
#pragma unroll
      for (int mq = 0; mq < 2; mq++)
#pragma unroll
        for (int kk = 0; kk < 2; kk++)
          afr[mq][kk] = *(short8*)&As[bf][kk][wm * 128 + (2 * q + mq) * 16 + l16][quad * 8];

      if (T + 1 < NT) {
        if (q == 0) stA(T + 1, 0);
        else if (q == 1) stA(T + 1, 1);
        else if (q == 2) stB(T + 1, 0);
        else stB(T + 1, 1);
      }

      __builtin_amdgcn_s_setprio(1);
#pragma unroll
      for (int mq = 0; mq < 2; mq++)
#pragma unroll
        for (int nf = 0; nf < 4; nf++)
#pragma unroll
          for (int kk = 0; kk < 2; kk++)
            acc[2 * q + mq][nf] = __builtin_amdgcn_mfma_f32_16x16x32_bf16(
                afr[mq][kk], bfr[nf][kk], acc[2 * q + mq][nf], 0, 0, 0);
      __builtin_amdgcn_s_setprio(0);
      PHASE_BAR();
    }
  }

  // epilogue
#pragma unroll
  for (int mf = 0; mf < 8; mf++) {
#pragma unroll
    for (int r = 0; r < 4; r++) {
      size_t rg = (size_t)(m0 + wm * 128 + mf * 16 + quad * 4 + r);
#pragma unroll
      for (int nf = 0; nf < 4; nf++) {
        int cg = n0 + wn * 64 + nf * 16 + l16;
        C[rg * N + cg] = f2bf(acc[mf][nf][r]);
      }
    }
  }
}

// ---------------- vectorized RoPE on fused QKV ----------------
// Q heads prescaled by 0.125*log2(e) (exp2-domain softmax downstream).
// thread = (tok, hh<40, g<4): handles dims [g*8, g*8+8) and [g*8+32, g*8+40).
__global__ __launch_bounds__(256) void rope_qk(ushort* __restrict__ t,
                                               const float* __restrict__ fc,
                                               const float* __restrict__ fs,
                                               int total) {
  int idx = blockIdx.x * blockDim.x + threadIdx.x;
  if (idx >= total) return;
  int g = idx & 3;
  int hh = (idx >> 2) % 40;
  int tok = idx / 160;
  int s = tok & (SEQ - 1);
  float scale = (hh < 32) ? 0.125f * LOG2E : 1.0f;
  ushort* p = t + (size_t)tok * QKV_LD + hh * 64 + g * 8;
  union { uint4 v; ushort u[8]; } lo, hi, olo, ohi;
  lo.v = *(const uint4*)p;
  hi.v = *(const uint4*)(p + 32);
  const float* fcb = fc + s * HDIM + g * 8;
  const float* fsb = fs + s * HDIM + g * 8;
  float4 c0a = ((const float4*)fcb)[0], c0b = ((const float4*)fcb)[1];
  float4 s0a = ((const float4*)fsb)[0], s0b = ((const float4*)fsb)[1];
  float4 c1a = ((const float4*)(fcb + 32))[0], c1b = ((const float4*)(fcb + 32))[1];
  float4 s1a = ((const float4*)(fsb + 32))[0], s1b = ((const float4*)(fsb + 32))[1];
  float cc0[8] = {c0a.x, c0a.y, c0a.z, c0a.w, c0b.x, c0b.y, c0b.z, c0b.w};
  float ss0[8] = {s0a.x, s0a.y, s0a.z, s0a.w, s0b.x, s0b.y, s0b.z, s0b.w};
  float cc1[8] = {c1a.x, c1a.y, c1a.z, c1a.w, c1b.x, c1b.y, c1b.z, c1b.w};
  float ss1[8] = {s1a.x, s1a.y, s1a.z, s1a.w, s1b.x, s1b.y, s1b.z, s1b.w};
#pragma unroll
  for (int j = 0; j < 8; j++) {
    float x0 = bf2f(lo.u[j]), x1 = bf2f(hi.u[j]);
    olo.u[j] = f2bf((x0 * cc0[j] - x1 * ss0[j]) * scale);
    ohi.u[j] = f2bf((x1 * cc1[j] + x0 * ss1[j]) * scale);
  }
  *(uint4*)p = olo.v;
  *(uint4*)(p + 32) = ohi.v;
}

// ---------------- MFMA flash attention v6 (CU-balanced, frozen) ----------------
__global__ __launch_bounds__(256, 4) void attn_mfma(const ushort* __restrict__ QKV,
                                                    ushort* __restrict__ O) {
  __shared__ ushort Ks[64][72];     // [key][d]
  __shared__ ushort Vt[64][72];     // [d][key]
  __shared__ ushort Pw[4][16][72];  // per-wave P[q][key], reused per frag
  const int tid = threadIdx.x;
  const int lane = tid & 63, wave = tid >> 6;
  const int quad = lane >> 4, l16 = lane & 15;

  // CU-balanced (qblk, bh) derivation
  const int bid = blockIdx.x;
  const int qq = bid >> 8;         // quarter 0..3
  const int j4 = (bid >> 6) & 3;   // 0..3
  const int bh = bid & 63;
  const int qblk = (qq >> 1) * 8 + ((qq & 1) ? 7 - j4 : j4);

  const int b = bh >> 5, h = bh & 31, kh = h >> 2;
  const int ntiles = 2 * qblk + 2;          // causal K-range of this 128-row block
  const int wrow = qblk * 128 + wave * 32;  // this wave's first q row (global)

  // Q fragments: f=0 rows [wrow, wrow+16), f=1 rows [wrow+16, wrow+32)
  short8 qf[2][2];
#pragma unroll
  for (int f = 0; f < 2; f++)
#pragma unroll
    for (int c = 0; c < 2; c++)
      qf[f][c] = *(const short8*)(QKV +
          (size_t)(b * SEQ + wrow + f * 16 + l16) * QKV_LD +
          h * HDIM + c * 32 + quad * 8);

  f32x4 o[2][4] = {};
  float m[2] = {-INFINITY, -INFINITY}, l[2] = {0.f, 0.f};

  const ushort* Kbase = QKV + (size_t)b * SEQ * QKV_LD + 2048 + kh * HDIM;
  const ushort* Vbase = Kbase + 512;
  const int kp = tid & 31, dg = tid >> 5;

  for (int t = 0; t < ntiles; t++) {
    const int k0 = t * 64;
    __syncthreads();
    {
      const float4* kpp = (const float4*)(Kbase + (size_t)(k0 + lane) * QKV_LD + wave * 16);
      float4 kv0 = kpp[0], kv1 = kpp[1];
      const uint4* va4 = (const uint4*)(Vbase + (size_t)(k0 + 2 * kp) * QKV_LD + dg * 8);
      const uint4* vb4 = (const uint4*)(Vbase + (size_t)(k0 + 2 * kp + 1) * QKV_LD + dg * 8);
      uint4 va = va4[0], vb = vb4[0];
      *(float4*)&Ks[lane][wave * 16] = kv0;
      *(float4*)&Ks[lane][wave * 16 + 8] = kv1;
      const unsigned* vaw = (const unsigned*)&va;
      const unsigned* vbw = (const unsigned*)&vb;
#pragma unroll
      for (int j = 0; j < 8; j++) {
        unsigned pk = (j & 1)
            ? __builtin_amdgcn_perm(vbw[j >> 1], vaw[j >> 1], 0x07060302)
            : __builtin_amdgcn_perm(vbw[j >> 1], vaw[j >> 1], 0x05040100);
        *(unsigned*)&Vt[dg * 8 + j][2 * kp] = pk;
      }
    }
    __syncthreads();

    // wave fully below diagonal? (both frags fully masked -> only staging needed)
    if (k0 > wrow + 31) continue;
    const bool a0 = (k0 <= wrow + 15);  // frag 0 has any active keys

    // QK^T for both frags, kf shared
    f32x4 s0[4], s1[4];
    __builtin_amdgcn_s_setprio(1);
#pragma unroll
    for (int nt = 0; nt < 4; nt++) {
      short8 kf0 = *(short8*)&Ks[nt * 16 + l16][quad * 8];
      short8 kf1 = *(short8*)&Ks[nt * 16 + l16][32 + quad * 8];
      f32x4 z1 = {};
      z1 = __builtin_amdgcn_mfma_f32_16x16x32_bf16(kf0, qf[1][0], z1, 0, 0, 0);
      s1[nt] = __builtin_amdgcn_mfma_f32_16x16x32_bf16(kf1, qf[1][1], z1, 0, 0, 0);
      if (a0) {
        f32x4 z0 = {};
        z0 = __builtin_amdgcn_mfma_f32_16x16x32_bf16(kf0, qf[0][0], z0, 0, 0, 0);
        s0[nt] = __builtin_amdgcn_mfma_f32_16x16x32_bf16(kf1, qf[0][1], z0, 0, 0, 0);
      }
    }
    __builtin_amdgcn_s_setprio(0);

    // causal masking (diagonal region only)
    if (k0 + 63 > wrow + 16) {  // frag 1 diagonal
      const int lim1 = wrow + 16 + l16 - k0;
#pragma unroll
      for (int nt = 0; nt < 4; nt++)
#pragma unroll
        for (int r = 0; r < 4; r++)
          if (nt * 16 + quad * 4 + r > lim1) s1[nt][r] = -INFINITY;
    }
    if (a0 && k0 + 63 > wrow) {  // frag 0 diagonal
      const int lim0 = wrow + l16 - k0;
#pragma unroll
      for (int nt = 0; nt < 4; nt++)
#pragma unroll
        for (int r = 0; r < 4; r++)
          if (nt * 16 + quad * 4 + r > lim0) s0[nt][r] = -INFINITY;
    }

    // online softmax (T13 defer-max), Pw reused per frag
    auto smx = [&](f32x4 (&s)[4], float& mm, float& ll, f32x4 (&oo)[4]) {
      float mx = s[0][0];
#pragma unroll
      for (int nt = 0; nt < 4; nt++)
#pragma unroll
        for (int r = 0; r < 4; r++) mx = fmaxf(mx, s[nt][r]);
      mx = fmaxf(mx, __shfl_xor(mx, 16));
      mx = fmaxf(mx, __shfl_xor(mx, 32));
      if (!__all(mx <= mm + 8.f)) {
        float mnew = fmaxf(mm, mx);
        float al = hw_exp2(mm - mnew);
        mm = mnew;
        ll *= al;
#pragma unroll
        for (int dt = 0; dt < 4; dt++)
#pragma unroll
          for (int r = 0; r < 4; r++) oo[dt][r] *= al;
      }
      float psum = 0.f;
#pragma unroll
      for (int nt = 0; nt < 4; nt++) {
        float p0 = hw_exp2(s[nt][0] - mm), p1 = hw_exp2(s[nt][1] - mm);
        float p2 = hw_exp2(s[nt][2] - mm), p3 = hw_exp2(s[nt][3] - mm);
        psum += (p0 + p1) + (p2 + p3);
        unsigned lo = __builtin_amdgcn_perm(fbits(p1), fbits(p0), 0x07060302);
        unsigned hi = __builtin_amdgcn_perm(fbits(p3), fbits(p2), 0x07060302);
        uint2 pk; pk.x = lo; pk.y = hi;
        *(uint2*)&Pw[wave][l16][nt * 16 + quad * 4] = pk;
      }
      psum += __shfl_xor(psum, 16);
      psum += __shfl_xor(psum, 32);
      ll += psum;
    };

    short8 pf00, pf01, pf10, pf11;
    if (a0) {
      smx(s0, m[0], l[0], o[0]);
      pf00 = *(short8*)&Pw[wave][l16][quad * 8];
      pf01 = *(short8*)&Pw[wave][l16][32 + quad * 8];
    }
    smx(s1, m[1], l[1], o[1]);
    pf10 = *(short8*)&Pw[wave][l16][quad * 8];
    pf11 = *(short8*)&Pw[wave][l16][32 + quad * 8];

    // PV for both frags, vf shared
    __builtin_amdgcn_s_setprio(1);
#pragma unroll
    for (int dt = 0; dt < 4; dt++) {
      short8 vf0 = *(short8*)&Vt[dt * 16 + l16][quad * 8];
      short8 vf1 = *(short8*)&Vt[dt * 16 + l16][32 + quad * 8];
      o[1][dt] = __builtin_amdgcn_mfma_f32_16x16x32_bf16(vf0, pf10, o[1][dt], 0, 0, 0);
      o[1][dt] = __builtin_amdgcn_mfma_f32_16x16x32_bf16(vf1, pf11, o[1][dt], 0, 0, 0);
      if (a0) {
        o[0][dt] = __builtin_amdgcn_mfma_f32_16x16x32_bf16(vf0, pf00, o[0][dt], 0, 0, 0);
        o[0][dt] = __builtin_amdgcn_mfma_f32_16x16x32_bf16(vf1, pf01, o[0][dt], 0, 0, 0);
      }
    }
    __builtin_amdgcn_s_setprio(0);
  }

#pragma unroll
  for (int f = 0; f < 2; f++) {
    float inv = 1.0f / l[f];
    size_t rowg = (size_t)(b * SEQ + wrow + f * 16 + l16) * EMBED + h * HDIM;
#pragma unroll
    for (int dt = 0; dt < 4; dt++) {
      ushort q0 = f2bf(o[f][dt][0] * inv), q1 = f2bf(o[f][dt][1] * inv);
      ushort q2 = f2bf(o[f][dt][2] * inv), q3 = f2bf(o[f][dt][3] * inv);
      uint2 pk;
      pk.x = (unsigned)q0 | ((unsigned)q1 << 16);
      pk.y = (unsigned)q2 | ((unsigned)q3 << 16);
      *(uint2*)&O[rowg + dt * 16 + quad * 4] = pk;
    }
  }
}

// ---------------- launch ----------------
extern "C" void kernel_launch(void* const* d_in, const int* in_sizes, int n_in,
                              void* d_out, int out_size, void* d_ws, size_t ws_size,
                              hipStream_t stream) {
  const float* x = (const float*)d_in[0];
  const float* fcos = (const float*)d_in[1];
  const float* fsin = (const float*)d_in[2];
  const float* wq = (const float*)d_in[3];
  const float* wk = (const float*)d_in[4];
  const float* wv = (const float*)d_in[5];
  const float* wo = (const float*)d_in[6];
  float* out = (float*)d_out;

  const int M = BATCH * SEQ;  // 4096
  ushort* ws = (ushort*)d_ws;
  ushort* xb = ws;
  ushort* wqkv = xb + (size_t)M * EMBED;
  ushort* wob = wqkv + (size_t)QKV_LD * EMBED;
  ushort* QKVb = wob + (size_t)EMBED * EMBED;
  ushort* Ab = QKVb + (size_t)M * QKV_LD;

  dim3 blk(256);
  // all conversions in one launch: 18874368 elems / 8 per thread / 256
  cvt_all<<<9216, blk, 0, stream>>>(x, wq, wk, wv, wo, xb, wqkv, wob);

  // QKV projection: 256x256 8-phase GEMM (192 blocks, 1/CU)
  gemm8p<<<dim3(QKV_LD / 256, M / 256), dim3(512), 0, stream>>>(xb, wqkv, QKVb, M, QKV_LD, EMBED);

  {
    int tot = M * 40 * 4;  // 655360 threads, 16 dims per thread
    rope_qk<<<(tot + 255) / 256, blk, 0, stream>>>(QKVb, fcos, fsin, tot);
  }

  attn_mfma<<<dim3(1024), blk, 0, stream>>>(QKVb, Ab);

  gemm_bf16<float><<<dim3(EMBED / 128, M / 128), blk, 0, stream>>>(Ab, wob, out, M, EMBED, EMBED);
}

// Round 7
// 317.619 us; speedup vs baseline: 1.2411x; 1.0146x over previous
//
#include <hip/hip_runtime.h>

#define BATCH 2
#define SEQ 2048
#define EMBED 2048
#define NHEADS 32
#define NKV 8
#define HDIM 64
#define QKV_LD 3072  // fused [Q(2048) | K(512) | V(512)] row stride
#define LOG2E 1.44269504088896f

typedef __attribute__((ext_vector_type(8))) short short8;
typedef __attribute__((ext_vector_type(4))) float f32x4;

__device__ inline float hw_exp2(float x) { return __builtin_amdgcn_exp2f(x); }

__device__ inline ushort f2bf(float f) {
  union { float f; unsigned u; } v{f};
  unsigned r = v.u + 0x7FFF + ((v.u >> 16) & 1);
  return (ushort)(r >> 16);
}
__device__ inline float bf2f(ushort u) {
  union { unsigned u; float f; } v{((unsigned)u) << 16};
  return v.f;
}
__device__ inline unsigned fbits(float f) {
  union { float f; unsigned u; } v{f};
  return v.u;
}

__device__ inline void gload16(const ushort* g, ushort* l) {
  __builtin_amdgcn_global_load_lds(
      (const __attribute__((address_space(1))) unsigned*)g,
      (__attribute__((address_space(3))) unsigned*)l, 16, 0, 0);
}

#define PHASE_BAR()                          \
  do {                                       \
    __builtin_amdgcn_sched_barrier(0);       \
    __builtin_amdgcn_s_barrier();            \
    __builtin_amdgcn_sched_barrier(0);       \
  } while (0)

// ---------------- fused fp32 -> bf16 convert (all 5 tensors, 1 launch) ----------------
// element ranges: x[0,8388608) wq[..12582912) wk[..13631488) wv[..14680064) wo[..18874368)
__global__ __launch_bounds__(256) void cvt_all(const float* __restrict__ x,
                                               const float* __restrict__ wq,
                                               const float* __restrict__ wk,
                                               const float* __restrict__ wv,
                                               const float* __restrict__ wo,
                                               ushort* __restrict__ xb,
                                               ushort* __restrict__ wqkv,
                                               ushort* __restrict__ wob) {
  size_t e = (size_t)(blockIdx.x * blockDim.x + threadIdx.x) * 8;
  const float* src;
  ushort* dst;
  if (e < 8388608u) { src = x + e; dst = xb + e; }
  else if (e < 12582912u) { size_t o = e - 8388608u; src = wq + o; dst = wqkv + o; }
  else if (e < 13631488u) { size_t o = e - 12582912u; src = wk + o; dst = wqkv + 4194304u + o; }
  else if (e < 14680064u) { size_t o = e - 13631488u; src = wv + o; dst = wqkv + 5242880u + o; }
  else { size_t o = e - 14680064u; src = wo + o; dst = wob + o; }
  float4 v0 = ((const float4*)src)[0];
  float4 v1 = ((const float4*)src)[1];
  union { uint4 v; ushort u[8]; } pk;
  pk.u[0] = f2bf(v0.x); pk.u[1] = f2bf(v0.y); pk.u[2] = f2bf(v0.z); pk.u[3] = f2bf(v0.w);
  pk.u[4] = f2bf(v1.x); pk.u[5] = f2bf(v1.y); pk.u[6] = f2bf(v1.z); pk.u[7] = f2bf(v1.w);
  *(uint4*)dst = pk.v;
}

// ---------------- 8-phase bf16 GEMM template (m201-class): C[M,N] = A * B^T ----------
// 512 threads = 8 waves (2M x 4N). Tile = 256(M) x BN(N), BK=64.
// BN=256: per-wave out 128x64, LDS 128KB, grid 1 blk/CU at nwg<=256.
// BN=128: per-wave out 128x32, LDS 96KB  (B half-sized) -> grid 256 blks = 1/CU
//         for N=2048 (BN=256 would give 128 blks = half the CUs idle).
// Per K-tile T: 4 phases x (4*NF) MFMA. B-frags read once (phase 0), A-frags per
// phase. Phase q stages part of tile T+1 into the OTHER buffer (A0,A1,B0[,B1]) ->
// no intra-tile WAR; vmcnt(0) once per K-tile at the top: T's loads were issued
// 1-4 phases earlier, latency hidden under MFMA.
template <int BN, typename OutT>
__global__ __launch_bounds__(512) void gemm8p(const ushort* __restrict__ Ag,
                                              const ushort* __restrict__ Bg,
                                              OutT* __restrict__ C,
                                              int M, int N, int K) {
  constexpr int NF = BN / 64;  // per-wave 16-col fragments
  __shared__ ushort As[2][2][256][32];
  __shared__ ushort Bs[2][2][BN][32];
  const int tid = threadIdx.x;
  const int lane = tid & 63, wave = tid >> 6;
  const int quad = lane >> 4, l16 = lane & 15;
  const int wm = wave >> 2, wn = wave & 3;  // 2M x 4N
  const int m0 = blockIdx.y * 256, n0 = blockIdx.x * BN;
  const int NT = K >> 6;

  // stage helpers: one half-tile (128 rows); this wave covers 16 rows,
  // 2 gload16 calls (one per kk subtile). LDS dest wave-uniform; source per-lane.
  auto stA = [&](int Tn, int h) {
    const int r0 = h * 128 + wave * 16;
    const ushort* g = Ag + (size_t)(m0 + r0 + (lane >> 2)) * K + Tn * 64 + (lane & 3) * 8;
    gload16(g, &As[Tn & 1][0][r0][0]);
    gload16(g + 32, &As[Tn & 1][1][r0][0]);
  };
  auto stB = [&](int Tn, int h) {
    const int r0 = h * 128 + wave * 16;
    const ushort* g = Bg + (size_t)(n0 + r0 + (lane >> 2)) * K + Tn * 64 + (lane & 3) * 8;
    gload16(g, &Bs[Tn & 1][0][r0][0]);
    gload16(g + 32, &Bs[Tn & 1][1][r0][0]);
  };

  f32x4 acc[8][NF] = {};

  // prologue: stage K-tile 0 fully
  stA(0, 0); stA(0, 1);
  stB(0, 0);
  if constexpr (BN == 256) stB(0, 1);

  for (int T = 0; T < NT; ++T) {
    const int bf = T & 1;
    asm volatile("s_waitcnt vmcnt(0)" ::: "memory");
    PHASE_BAR();

    // B-frags for the whole K-tile (phase 0 reads)
    short8 bfr[NF][2];
#pragma unroll
    for (int nf = 0; nf < NF; nf++)
#pragma unroll
      for (int kk = 0; kk < 2; kk++)
        bfr[nf][kk] = *(short8*)&Bs[bf][kk][wn * (16 * NF) + nf * 16 + l16][quad * 8];

#pragma unroll
    for (int q = 0; q < 4; q++) {
      short8 afr[2][2];
#pragma unroll
      for (int mq = 0; mq < 2; mq++)
#pragma unroll
        for (int kk = 0; kk < 2; kk++)
          afr[mq][kk] = *(short8*)&As[bf][kk][wm * 128 + (2 * q + mq) * 16 + l16][quad * 8];

      if (T + 1 < NT) {
        if (q == 0) stA(T + 1, 0);
        else if (q == 1) stA(T + 1, 1);
        else if (q == 2) stB(T + 1, 0);
        else if constexpr (BN == 256) stB(T + 1, 1);
      }

      __builtin_amdgcn_s_setprio(1);
#pragma unroll
      for (int mq = 0; mq < 2; mq++)
#pragma unroll
        for (int nf = 0; nf < NF; nf++)
#pragma unroll
          for (int kk = 0; kk < 2; kk++)
            acc[2 * q + mq][nf] = __builtin_amdgcn_mfma_f32_16x16x32_bf16(
                afr[mq][kk], bfr[nf][kk], acc[2 * q + mq][nf], 0, 0, 0);
      __builtin_amdgcn_s_setprio(0);
      PHASE_BAR();
    }
  }

  // epilogue
#pragma unroll
  for (int mf = 0; mf < 8; mf++) {
#pragma unroll
    for (int r = 0; r < 4; r++) {
      size_t rg = (size_t)(m0 + wm * 128 + mf * 16 + quad * 4 + r);
#pragma unroll
      for (int nf = 0; nf < NF; nf++) {
        int cg = n0 + wn * (16 * NF) + nf * 16 + l16;
        if constexpr (sizeof(OutT) == 2)
          C[rg * N + cg] = f2bf(acc[mf][nf][r]);
        else
          C[rg * N + cg] = acc[mf][nf][r];
      }
    }
  }
}

// ---------------- vectorized RoPE on fused QKV ----------------
// Q heads prescaled by 0.125*log2(e) (exp2-domain softmax downstream).
// thread = (tok, hh<40, g<4): handles dims [g*8, g*8+8) and [g*8+32, g*8+40).
__global__ __launch_bounds__(256) void rope_qk(ushort* __restrict__ t,
                                               const float* __restrict__ fc,
                                               const float* __restrict__ fs,
                                               int total) {
  int idx = blockIdx.x * blockDim.x + threadIdx.x;
  if (idx >= total) return;
  int g = idx & 3;
  int hh = (idx >> 2) % 40;
  int tok = idx / 160;
  int s = tok & (SEQ - 1);
  float scale = (hh < 32) ? 0.125f * LOG2E : 1.0f;
  ushort* p = t + (size_t)tok * QKV_LD + hh * 64 + g * 8;
  union { uint4 v; ushort u[8]; } lo, hi, olo, ohi;
  lo.v = *(const uint4*)p;
  hi.v = *(const uint4*)(p + 32);
  const float* fcb = fc + s * HDIM + g * 8;
  const float* fsb = fs + s * HDIM + g * 8;
  float4 c0a = ((const float4*)fcb)[0], c0b = ((const float4*)fcb)[1];
  float4 s0a = ((const float4*)fsb)[0], s0b = ((const float4*)fsb)[1];
  float4 c1a = ((const float4*)(fcb + 32))[0], c1b = ((const float4*)(fcb + 32))[1];
  float4 s1a = ((const float4*)(fsb + 32))[0], s1b = ((const float4*)(fsb + 32))[1];
  float cc0[8] = {c0a.x, c0a.y, c0a.z, c0a.w, c0b.x, c0b.y, c0b.z, c0b.w};
  float ss0[8] = {s0a.x, s0a.y, s0a.z, s0a.w, s0b.x, s0b.y, s0b.z, s0b.w};
  float cc1[8] = {c1a.x, c1a.y, c1a.z, c1a.w, c1b.x, c1b.y, c1b.z, c1b.w};
  float ss1[8] = {s1a.x, s1a.y, s1a.z, s1a.w, s1b.x, s1b.y, s1b.z, s1b.w};
#pragma unroll
  for (int j = 0; j < 8; j++) {
    float x0 = bf2f(lo.u[j]), x1 = bf2f(hi.u[j]);
    olo.u[j] = f2bf((x0 * cc0[j] - x1 * ss0[j]) * scale);
    ohi.u[j] = f2bf((x1 * cc1[j] + x0 * ss1[j]) * scale);
  }
  *(uint4*)p = olo.v;
  *(uint4*)(p + 32) = ohi.v;
}

// ---------------- MFMA flash attention v6 (CU-balanced, frozen) ----------------
__global__ __launch_bounds__(256, 4) void attn_mfma(const ushort* __restrict__ QKV,
                                                    ushort* __restrict__ O) {
  __shared__ ushort Ks[64][72];     // [key][d]
  __shared__ ushort Vt[64][72];     // [d][key]
  __shared__ ushort Pw[4][16][72];  // per-wave P[q][key], reused per frag
  const int tid = threadIdx.x;
  const int lane = tid & 63, wave = tid >> 6;
  const int quad = lane >> 4, l16 = lane & 15;

  // CU-balanced (qblk, bh) derivation
  const int bid = blockIdx.x;
  const int qq = bid >> 8;         // quarter 0..3
  const int j4 = (bid >> 6) & 3;   // 0..3
  const int bh = bid & 63;
  const int qblk = (qq >> 1) * 8 + ((qq & 1) ? 7 - j4 : j4);

  const int b = bh >> 5, h = bh & 31, kh = h >> 2;
  const int ntiles = 2 * qblk + 2;          // causal K-range of this 128-row block
  const int wrow = qblk * 128 + wave * 32;  // this wave's first q row (global)

  // Q fragments: f=0 rows [wrow, wrow+16), f=1 rows [wrow+16, wrow+32)
  short8 qf[2][2];
#pragma unroll
  for (int f = 0; f < 2; f++)
#pragma unroll
    for (int c = 0; c < 2; c++)
      qf[f][c] = *(const short8*)(QKV +
          (size_t)(b * SEQ + wrow + f * 16 + l16) * QKV_LD +
          h * HDIM + c * 32 + quad * 8);

  f32x4 o[2][4] = {};
  float m[2] = {-INFINITY, -INFINITY}, l[2] = {0.f, 0.f};

  const ushort* Kbase = QKV + (size_t)b * SEQ * QKV_LD + 2048 + kh * HDIM;
  const ushort* Vbase = Kbase + 512;
  const int kp = tid & 31, dg = tid >> 5;

  for (int t = 0; t < ntiles; t++) {
    const int k0 = t * 64;
    __syncthreads();
    {
      const float4* kpp = (const float4*)(Kbase + (size_t)(k0 + lane) * QKV_LD + wave * 16);
      float4 kv0 = kpp[0], kv1 = kpp[1];
      const uint4* va4 = (const uint4*)(Vbase + (size_t)(k0 + 2 * kp) * QKV_LD + dg * 8);
      const uint4* vb4 = (const uint4*)(Vbase + (size_t)(k0 + 2 * kp + 1) * QKV_LD + dg * 8);
      uint4 va = va4[0], vb = vb4[0];
      *(float4*)&Ks[lane][wave * 16] = kv0;
      *(float4*)&Ks[lane][wave * 16 + 8] = kv1;
      const unsigned* vaw = (const unsigned*)&va;
      const unsigned* vbw = (const unsigned*)&vb;
#pragma unroll
      for (int j = 0; j < 8; j++) {
        unsigned pk = (j & 1)
            ? __builtin_amdgcn_perm(vbw[j >> 1], vaw[j >> 1], 0x07060302)
            : __builtin_amdgcn_perm(vbw[j >> 1], vaw[j >> 1], 0x05040100);
        *(unsigned*)&Vt[dg * 8 + j][2 * kp] = pk;
      }
    }
    __syncthreads();

    // wave fully below diagonal? (both frags fully masked -> only staging needed)
    if (k0 > wrow + 31) continue;
    const bool a0 = (k0 <= wrow + 15);  // frag 0 has any active keys

    // QK^T for both frags, kf shared
    f32x4 s0[4], s1[4];
    __builtin_amdgcn_s_setprio(1);
#pragma unroll
    for (int nt = 0; nt < 4; nt++) {
      short8 kf0 = *(short8*)&Ks[nt * 16 + l16][quad * 8];
      short8 kf1 = *(short8*)&Ks[nt * 16 + l16][32 + quad * 8];
      f32x4 z1 = {};
      z1 = __builtin_amdgcn_mfma_f32_16x16x32_bf16(kf0, qf[1][0], z1, 0, 0, 0);
      s1[nt] = __builtin_amdgcn_mfma_f32_16x16x32_bf16(kf1, qf[1][1], z1, 0, 0, 0);
      if (a0) {
        f32x4 z0 = {};
        z0 = __builtin_amdgcn_mfma_f32_16x16x32_bf16(kf0, qf[0][0], z0, 0, 0, 0);
        s0[nt] = __builtin_amdgcn_mfma_f32_16x16x32_bf16(kf1, qf[0][1], z0, 0, 0, 0);
      }
    }
    __builtin_amdgcn_s_setprio(0);

    // causal masking (diagonal region only)
    if (k0 + 63 > wrow + 16) {  // frag 1 diagonal
      const int lim1 = wrow + 16 + l16 - k0;
#pragma unroll
      for (int nt = 0; nt < 4; nt++)
#pragma unroll
        for (int r = 0; r < 4; r++)
          if (nt * 16 + quad * 4 + r > lim1) s1[nt][r] = -INFINITY;
    }
    if (a0 && k0 + 63 > wrow) {  // frag 0 diagonal
      const int lim0 = wrow + l16 - k0;
#pragma unroll
      for (int nt = 0; nt < 4; nt++)
#pragma unroll
        for (int r = 0; r < 4; r++)
          if (nt * 16 + quad * 4 + r > lim0) s0[nt][r] = -INFINITY;
    }

    // online softmax (T13 defer-max), Pw reused per frag
    auto smx = [&](f32x4 (&s)[4], float& mm, float& ll, f32x4 (&oo)[4]) {
      float mx = s[0][0];
#pragma unroll
      for (int nt = 0; nt < 4; nt++)
#pragma unroll
        for (int r = 0; r < 4; r++) mx = fmaxf(mx, s[nt][r]);
      mx = fmaxf(mx, __shfl_xor(mx, 16));
      mx = fmaxf(mx, __shfl_xor(mx, 32));
      if (!__all(mx <= mm + 8.f)) {
        float mnew = fmaxf(mm, mx);
        float al = hw_exp2(mm - mnew);
        mm = mnew;
        ll *= al;
#pragma unroll
        for (int dt = 0; dt < 4; dt++)
#pragma unroll
          for (int r = 0; r < 4; r++) oo[dt][r] *= al;
      }
      float psum = 0.f;
#pragma unroll
      for (int nt = 0; nt < 4; nt++) {
        float p0 = hw_exp2(s[nt][0] - mm), p1 = hw_exp2(s[nt][1] - mm);
        float p2 = hw_exp2(s[nt][2] - mm), p3 = hw_exp2(s[nt][3] - mm);
        psum += (p0 + p1) + (p2 + p3);
        unsigned lo = __builtin_amdgcn_perm(fbits(p1), fbits(p0), 0x07060302);
        unsigned hi = __builtin_amdgcn_perm(fbits(p3), fbits(p2), 0x07060302);
        uint2 pk; pk.x = lo; pk.y = hi;
        *(uint2*)&Pw[wave][l16][nt * 16 + quad * 4] = pk;
      }
      psum += __shfl_xor(psum, 16);
      psum += __shfl_xor(psum, 32);
      ll += psum;
    };

    short8 pf00, pf01, pf10, pf11;
    if (a0) {
      smx(s0, m[0], l[0], o[0]);
      pf00 = *(short8*)&Pw[wave][l16][quad * 8];
      pf01 = *(short8*)&Pw[wave][l16][32 + quad * 8];
    }
    smx(s1, m[1], l[1], o[1]);
    pf10 = *(short8*)&Pw[wave][l16][quad * 8];
    pf11 = *(short8*)&Pw[wave][l16][32 + quad * 8];

    // PV for both frags, vf shared
    __builtin_amdgcn_s_setprio(1);
#pragma unroll
    for (int dt = 0; dt < 4; dt++) {
      short8 vf0 = *(short8*)&Vt[dt * 16 + l16][quad * 8];
      short8 vf1 = *(short8*)&Vt[dt * 16 + l16][32 + quad * 8];
      o[1][dt] = __builtin_amdgcn_mfma_f32_16x16x32_bf16(vf0, pf10, o[1][dt], 0, 0, 0);
      o[1][dt] = __builtin_amdgcn_mfma_f32_16x16x32_bf16(vf1, pf11, o[1][dt], 0, 0, 0);
      if (a0) {
        o[0][dt] = __builtin_amdgcn_mfma_f32_16x16x32_bf16(vf0, pf00, o[0][dt], 0, 0, 0);
        o[0][dt] = __builtin_amdgcn_mfma_f32_16x16x32_bf16(vf1, pf01, o[0][dt], 0, 0, 0);
      }
    }
    __builtin_amdgcn_s_setprio(0);
  }

#pragma unroll
  for (int f = 0; f < 2; f++) {
    float inv = 1.0f / l[f];
    size_t rowg = (size_t)(b * SEQ + wrow + f * 16 + l16) * EMBED + h * HDIM;
#pragma unroll
    for (int dt = 0; dt < 4; dt++) {
      ushort q0 = f2bf(o[f][dt][0] * inv), q1 = f2bf(o[f][dt][1] * inv);
      ushort q2 = f2bf(o[f][dt][2] * inv), q3 = f2bf(o[f][dt][3] * inv);
      uint2 pk;
      pk.x = (unsigned)q0 | ((unsigned)q1 << 16);
      pk.y = (unsigned)q2 | ((unsigned)q3 << 16);
      *(uint2*)&O[rowg + dt * 16 + quad * 4] = pk;
    }
  }
}

// ---------------- launch ----------------
extern "C" void kernel_launch(void* const* d_in, const int* in_sizes, int n_in,
                              void* d_out, int out_size, void* d_ws, size_t ws_size,
                              hipStream_t stream) {
  const float* x = (const float*)d_in[0];
  const float* fcos = (const float*)d_in[1];
  const float* fsin = (const float*)d_in[2];
  const float* wq = (const float*)d_in[3];
  const float* wk = (const float*)d_in[4];
  const float* wv = (const float*)d_in[5];
  const float* wo = (const float*)d_in[6];
  float* out = (float*)d_out;

  const int M = BATCH * SEQ;  // 4096
  ushort* ws = (ushort*)d_ws;
  ushort* xb = ws;
  ushort* wqkv = xb + (size_t)M * EMBED;
  ushort* wob = wqkv + (size_t)QKV_LD * EMBED;
  ushort* QKVb = wob + (size_t)EMBED * EMBED;
  ushort* Ab = QKVb + (size_t)M * QKV_LD;

  dim3 blk(256);
  // all conversions in one launch: 18874368 elems / 8 per thread / 256
  cvt_all<<<9216, blk, 0, stream>>>(x, wq, wk, wv, wo, xb, wqkv, wob);

  // QKV projection: 256x256 8-phase GEMM (192 blocks, 1/CU)
  gemm8p<256, ushort><<<dim3(QKV_LD / 256, M / 256), dim3(512), 0, stream>>>(xb, wqkv, QKVb, M, QKV_LD, EMBED);

  {
    int tot = M * 40 * 4;  // 655360 threads, 16 dims per thread
    rope_qk<<<(tot + 255) / 256, blk, 0, stream>>>(QKVb, fcos, fsin, tot);
  }

  attn_mfma<<<dim3(1024), blk, 0, stream>>>(QKVb, Ab);

  // output projection: 256x128 8-phase GEMM (256 blocks = 1/CU)
  gemm8p<128, float><<<dim3(EMBED / 128, M / 256), dim3(512), 0, stream>>>(Ab, wob, out, M, EMBED, EMBED);
}